// Round 6
// baseline (241.574 us; speedup 1.0000x reference)
//
#include <hip/hip_runtime.h>

#define N_NODES 50000
#define N_EDGES 800000
#define DIM 128
#define N_REL 86
#define BATCH 2048
#define CAP 64               // per-node bucket capacity; max deg ~45 for Poisson(16)
#define ZROW N_NODES         // sentinel row: zeroed embedding row, dv[ZROW]=0

#define NP 196               // partitions by dst>>8 (256 nodes each; ceil(50000/256))
#define EB 196               // edge blocks for hist/scatter (4096 edges each)
#define PCAP 8192            // partition edge capacity (mean 4096, sigma 64)

#define NSLAB 4              // 32-dim slabs; slab working set 3.2 MB < 4 MB per-XCD L2
#define NODES_PER_BLK 32     // 256 threads / 8 lanes per node
#define NBLK ((N_NODES + NODES_PER_BLK - 1) / NODES_PER_BLK)    // 1563
#define SLAB_GRID (8 * ((NBLK + 1) / 2))                        // 6256

using bf16x8 = __attribute__((ext_vector_type(8))) short;
using f32x4  = __attribute__((ext_vector_type(4))) float;

// float -> bf16 round-to-nearest-even (finite inputs)
static __device__ __forceinline__ unsigned short f2bf(float f) {
  union { float f; unsigned int i; } v; v.f = f;
  unsigned int x = v.i;
  unsigned int r = x + 0x7FFFu + ((x >> 16) & 1u);
  return (unsigned short)(r >> 16);
}
static __device__ __forceinline__ float bf2f(unsigned short u) {
  union { unsigned int i; float f; } v;
  v.i = ((unsigned int)u) << 16;
  return v.f;
}

#define G_TQ    172           // 86 relations x 2 d-blocks
#define G_GEMM  391           // ceil(50000/128)
#define TPAD 136              // 128+8 bf16: 272 B row stride -> 2-way bank alias (free)
#define QPAD 136

// ---------------- kernel 0: weight prep + sentinel-row zeroing ----------------

__global__ __launch_bounds__(256) void k_prep(const float* __restrict__ W1, const float* __restrict__ W2,
                                              const float* __restrict__ M,
                                              unsigned short* __restrict__ W1th, unsigned short* __restrict__ W1tl,
                                              unsigned short* __restrict__ W2th, unsigned short* __restrict__ W2tl,
                                              unsigned short* __restrict__ Mth,
                                              unsigned short* __restrict__ hbuf1,
                                              unsigned short* __restrict__ hbuf2,
                                              float* __restrict__ dv) {
  int g = blockIdx.x * 256 + threadIdx.x;          // 16384 threads = DIM*DIM
  // zero the sentinel rows (gather pads resolve to ZROW; must be 0.0 not garbage/NaN)
  if (g < 32) {
    ushort4 z = {0, 0, 0, 0};
    ((ushort4*)hbuf1)[(size_t)ZROW * 32 + g] = z;
  } else if (g < 64) {
    ushort4 z = {0, 0, 0, 0};
    ((ushort4*)hbuf2)[(size_t)ZROW * 32 + (g - 32)] = z;
  } else if (g == 64) {
    dv[ZROW] = 0.f;
  }
  int k = g >> 7, n = g & 127;
  int t = n * DIM + k;
  float w1 = W1[g];
  unsigned short h1 = f2bf(w1);
  W1th[t] = h1;
  W1tl[t] = f2bf(w1 - bf2f(h1));
  float w2 = W2[g];
  unsigned short h2 = f2bf(w2);
  W2th[t] = h2;
  W2tl[t] = f2bf(w2 - bf2f(h2));
  Mth[t] = f2bf(M[g]);
}

// ---------------- build pass 1: per-block LDS histogram over dst>>8  ||  decoder TQ ----------------

__global__ __launch_bounds__(256) void k_histTQ(const int* __restrict__ dst,
                                                unsigned int* __restrict__ histBlk,
                                                const float* __restrict__ Rel,
                                                const unsigned short* __restrict__ Mth,
                                                unsigned short* __restrict__ Qbf) {
  __shared__ __align__(16) unsigned char smem[64 * TPAD * 2];   // max(hist 784B, Ts 17408B)
  int bid = blockIdx.x;
  union U { uint4 u; bf16x8 h; };

  if (bid < EB) {
    unsigned int* hist = (unsigned int*)smem;
    int t = threadIdx.x;
    if (t < NP) hist[t] = 0u;
    __syncthreads();
    #pragma unroll
    for (int j = 0; j < 4; ++j) {
      int i0 = bid * 4096 + j * 1024 + t * 4;
      if (i0 < N_EDGES) {
        int4 d4 = *(const int4*)(dst + i0);
        atomicAdd(&hist[d4.x >> 8], 1u);
        atomicAdd(&hist[d4.y >> 8], 1u);
        atomicAdd(&hist[d4.z >> 8], 1u);
        atomicAdd(&hist[d4.w >> 8], 1u);
      }
    }
    __syncthreads();
    if (t < NP) histBlk[bid * NP + t] = hist[t];
    return;
  }

  // ---- decoder precompute: T_r = Rel_r @ M (LDS), Q_r = T_r @ Rel_r^T ----
  unsigned short* Ts = (unsigned short*)smem;
  int wave = threadIdx.x >> 6, lane = threadIdx.x & 63;
  int l15 = lane & 15, quad = lane >> 4;
  int tb = bid - EB;                       // [0, 172)
  int r = tb >> 1, dblk = tb & 1;
  const float* Rr = Rel + (size_t)r * DIM * DIM;
  unsigned short* Qr = Qbf + (size_t)r * DIM * DIM;
  int dw = dblk * 64 + wave * 16;
  f32x4 acc[8];
  #pragma unroll
  for (int nt = 0; nt < 8; ++nt) acc[nt] = f32x4{0.f, 0.f, 0.f, 0.f};
  #pragma unroll
  for (int ks = 0; ks < 4; ++ks) {
    int k0 = ks * 32 + quad * 8;
    const float* ap = Rr + (size_t)(dw + l15) * DIM + k0;
    float av[8];
    *(float4*)(av)     = *(const float4*)(ap);
    *(float4*)(av + 4) = *(const float4*)(ap + 4);
    bf16x8 a;
    #pragma unroll
    for (int j = 0; j < 8; ++j) a[j] = (short)f2bf(av[j]);
    #pragma unroll
    for (int nt = 0; nt < 8; ++nt) {
      U b; b.u = *(const uint4*)(Mth + (nt * 16 + l15) * DIM + k0);
      acc[nt] = __builtin_amdgcn_mfma_f32_16x16x32_bf16(a, b.h, acc[nt], 0, 0, 0);
    }
  }
  #pragma unroll
  for (int nt = 0; nt < 8; ++nt)
    #pragma unroll
    for (int reg = 0; reg < 4; ++reg)
      Ts[(wave * 16 + quad * 4 + reg) * TPAD + nt * 16 + l15] = f2bf(acc[nt][reg]);
  __syncthreads();
  f32x4 qacc[8];
  #pragma unroll
  for (int nt = 0; nt < 8; ++nt) qacc[nt] = f32x4{0.f, 0.f, 0.f, 0.f};
  #pragma unroll
  for (int ks = 0; ks < 4; ++ks) {
    int k0 = ks * 32 + quad * 8;
    U a; a.u = *(const uint4*)(Ts + (wave * 16 + l15) * TPAD + k0);
    #pragma unroll
    for (int nt = 0; nt < 8; ++nt) {
      const float* bp = Rr + (size_t)(nt * 16 + l15) * DIM + k0;
      float bv[8];
      *(float4*)(bv)     = *(const float4*)(bp);
      *(float4*)(bv + 4) = *(const float4*)(bp + 4);
      bf16x8 b;
      #pragma unroll
      for (int j = 0; j < 8; ++j) b[j] = (short)f2bf(bv[j]);
      qacc[nt] = __builtin_amdgcn_mfma_f32_16x16x32_bf16(a.h, b, qacc[nt], 0, 0, 0);
    }
  }
  #pragma unroll
  for (int nt = 0; nt < 8; ++nt)
    #pragma unroll
    for (int reg = 0; reg < 4; ++reg)
      Qr[(size_t)(dw + quad * 4 + reg) * DIM + nt * 16 + l15] = f2bf(qacc[nt][reg]);
}

// ---------------- build pass 2: per-bin cross-block exclusive scan ----------------

__global__ __launch_bounds__(256) void k_scanB(const unsigned int* __restrict__ histBlk,
                                               unsigned int* __restrict__ blkoff,
                                               unsigned int* __restrict__ partCnt) {
  __shared__ unsigned int sd[256];
  int b = blockIdx.x;          // bin
  int t = threadIdx.x;
  unsigned int v = (t < EB) ? histBlk[t * NP + b] : 0u;
  sd[t] = v; __syncthreads();
  for (int off = 1; off < 256; off <<= 1) {
    unsigned int y = (t >= off) ? sd[t - off] : 0u;
    __syncthreads();
    sd[t] += y;
    __syncthreads();
  }
  if (t < EB) blkoff[t * NP + b] = (unsigned int)b * PCAP + sd[t] - v;
  if (t == EB - 1) partCnt[b] = sd[t];
}

// ---------------- build pass 3: scatter packed edges to partitions (LDS slotting)  ||  gemm1 ----------------
// pe entry: (dst & 255) << 17 | src     (src < 50000 < 2^17)

__global__ __launch_bounds__(256) void k_scatG(const int* __restrict__ src, const int* __restrict__ dst,
                                               const unsigned int* __restrict__ blkoff,
                                               unsigned int* __restrict__ pe,
                                               const float* __restrict__ x,
                                               const unsigned short* __restrict__ W1th,
                                               const unsigned short* __restrict__ W1tl,
                                               unsigned short* __restrict__ hout) {
  __shared__ unsigned int lcnt[NP];
  int bid = blockIdx.x;
  union U { uint4 u; bf16x8 h; };

  if (bid < EB) {
    int t = threadIdx.x;
    if (t < NP) lcnt[t] = blkoff[bid * NP + t];
    __syncthreads();
    #pragma unroll
    for (int j = 0; j < 4; ++j) {
      int i0 = bid * 4096 + j * 1024 + t * 4;
      if (i0 < N_EDGES) {
        int4 s4 = *(const int4*)(src + i0);
        int4 d4 = *(const int4*)(dst + i0);
        int b0 = d4.x >> 8, b1 = d4.y >> 8, b2 = d4.z >> 8, b3 = d4.w >> 8;
        unsigned int p0 = atomicAdd(&lcnt[b0], 1u);
        unsigned int p1 = atomicAdd(&lcnt[b1], 1u);
        unsigned int p2 = atomicAdd(&lcnt[b2], 1u);
        unsigned int p3 = atomicAdd(&lcnt[b3], 1u);
        if (p0 < (unsigned int)(b0 + 1) * PCAP) pe[p0] = ((unsigned)(d4.x & 255) << 17) | (unsigned)s4.x;
        if (p1 < (unsigned int)(b1 + 1) * PCAP) pe[p1] = ((unsigned)(d4.y & 255) << 17) | (unsigned)s4.y;
        if (p2 < (unsigned int)(b2 + 1) * PCAP) pe[p2] = ((unsigned)(d4.z & 255) << 17) | (unsigned)s4.z;
        if (p3 < (unsigned int)(b3 + 1) * PCAP) pe[p3] = ((unsigned)(d4.w & 255) << 17) | (unsigned)s4.w;
      }
    }
    return;
  }

  // ---- node GEMM layer 1: hout = x @ W1 (hi/lo 3-term, bf16 out) ----
  int wave = threadIdx.x >> 6, lane = threadIdx.x & 63;
  int l15 = lane & 15, quad = lane >> 4;
  int r0 = (bid - EB) * 128 + wave * 32;
  f32x4 acc[2][8];
  #pragma unroll
  for (int mt = 0; mt < 2; ++mt)
    #pragma unroll
    for (int nt = 0; nt < 8; ++nt) acc[mt][nt] = f32x4{0.f, 0.f, 0.f, 0.f};
  #pragma unroll
  for (int ks = 0; ks < 4; ++ks) {
    int k0 = ks * 32 + quad * 8;
    bf16x8 ah[2], al[2];
    #pragma unroll
    for (int mt = 0; mt < 2; ++mt) {
      int row = r0 + mt * 16 + l15;
      row = (row < N_NODES) ? row : (N_NODES - 1);
      const float* xp = x + (size_t)row * DIM + k0;
      float xv[8];
      *(float4*)(xv)     = *(const float4*)(xp);
      *(float4*)(xv + 4) = *(const float4*)(xp + 4);
      #pragma unroll
      for (int j = 0; j < 8; ++j) {
        unsigned short h = f2bf(xv[j]);
        ah[mt][j] = (short)h;
        al[mt][j] = (short)f2bf(xv[j] - bf2f(h));
      }
    }
    #pragma unroll
    for (int nt = 0; nt < 8; ++nt) {
      U bh, bl;
      bh.u = *(const uint4*)(W1th + (nt * 16 + l15) * DIM + k0);
      bl.u = *(const uint4*)(W1tl + (nt * 16 + l15) * DIM + k0);
      #pragma unroll
      for (int mt = 0; mt < 2; ++mt) {
        acc[mt][nt] = __builtin_amdgcn_mfma_f32_16x16x32_bf16(ah[mt], bh.h, acc[mt][nt], 0, 0, 0);
        acc[mt][nt] = __builtin_amdgcn_mfma_f32_16x16x32_bf16(al[mt], bh.h, acc[mt][nt], 0, 0, 0);
        acc[mt][nt] = __builtin_amdgcn_mfma_f32_16x16x32_bf16(ah[mt], bl.h, acc[mt][nt], 0, 0, 0);
      }
    }
  }
  #pragma unroll
  for (int mt = 0; mt < 2; ++mt)
    #pragma unroll
    for (int reg = 0; reg < 4; ++reg) {
      int row = r0 + mt * 16 + quad * 4 + reg;
      if (row < N_NODES) {
        #pragma unroll
        for (int nt = 0; nt < 8; ++nt)
          hout[(size_t)row * DIM + nt * 16 + l15] = f2bf(acc[mt][nt][reg]);
      }
    }
}

// ---------------- build pass 4: per-partition bucket fill + pad-to-8 + cnt + dinv ----------------

__global__ __launch_bounds__(256) void k_build(const unsigned int* __restrict__ pe,
                                               const unsigned int* __restrict__ partCnt,
                                               int* __restrict__ esrc, int* __restrict__ cnt,
                                               float* __restrict__ dv) {
  __shared__ unsigned int c256[256];
  int p = blockIdx.x, t = threadIdx.x;
  c256[t] = 0u;
  __syncthreads();
  int m = min((int)partCnt[p], PCAP);
  for (int i = t; i < m; i += 256) {
    unsigned int e = pe[(size_t)p * PCAP + i];
    unsigned int local = e >> 17;
    unsigned int s = e & 0x1FFFFu;
    unsigned int slot = atomicAdd(&c256[local], 1u);
    int node = p * 256 + (int)local;
    if (slot < CAP) esrc[(size_t)node * CAP + slot] = (int)s;
  }
  __syncthreads();
  int node = p * 256 + t;
  if (node < N_NODES) {
    int c = (int)c256[t];
    cnt[node] = c;
    dv[node] = rsqrtf((float)(c + 1));
    int padded = min((c + 7) & ~7, CAP);          // pad bucket to multiple of 8
    for (int s = c; s < padded; ++s) esrc[(size_t)node * CAP + s] = ZROW;
  }
}

// ---------------- agg1 by dim-slab: block = (32 nodes) x (one 32-dim slab), XCD-pair local ----------------
// slab working set = 50000 x 32 dims x 2B = 3.2 MB -> resident in one XCD's 4 MB L2.
// bid%8 -> XCD (round-robin heuristic, perf-only): slab = (bid&7)>>1 keeps each slab on 2 XCDs.
// 8 lanes per node: lane loads ushort4 (8B), group covers 64B row-slab per edge.

__global__ __launch_bounds__(256) void k_agg_slab(const unsigned short* __restrict__ h,
                                                  const int* __restrict__ cnt,
                                                  const float* __restrict__ dv,
                                                  const int* __restrict__ esrc,
                                                  const float* __restrict__ bias,
                                                  unsigned short* __restrict__ outh,
                                                  unsigned short* __restrict__ outl) {
  int bid = blockIdx.x;
  int slab = (bid & 7) >> 1;
  int nb = (bid >> 3) * 2 + (bid & 1);
  if (nb >= NBLK) return;
  int grp = threadIdx.x >> 3, lane8 = threadIdx.x & 7;
  int node = nb * NODES_PER_BLK + grp;
  if (node >= N_NODES) return;

  const ushort4* h4 = (const ushort4*)h;          // 32 x ushort4 per row
  int base4 = slab * 8 + lane8;                   // ushort4 index within row (this lane's 4 dims)
  int deg = cnt[node];
  int end = min((deg + 7) & ~7, CAP);             // padded multiple of 8
  float di = dv[node];
  ushort4 hv = h4[(size_t)node * 32 + base4];
  float ax = di * bf2f(hv.x), ay = di * bf2f(hv.y), az = di * bf2f(hv.z), aw = di * bf2f(hv.w);
  float bx = 0.f, by = 0.f, bz = 0.f, bw = 0.f;
  const int* eb = esrc + node * CAP;
  for (int e = 0; e < end; e += 8) {
    int4 sA = *(const int4*)(eb + e);             // uniform within group (broadcast)
    int4 sB = *(const int4*)(eb + e + 4);
    ushort4 v0 = h4[(size_t)sA.x * 32 + base4];
    ushort4 v1 = h4[(size_t)sA.y * 32 + base4];
    ushort4 v2 = h4[(size_t)sA.z * 32 + base4];
    ushort4 v3 = h4[(size_t)sA.w * 32 + base4];
    ushort4 v4 = h4[(size_t)sB.x * 32 + base4];
    ushort4 v5 = h4[(size_t)sB.y * 32 + base4];
    ushort4 v6 = h4[(size_t)sB.z * 32 + base4];
    ushort4 v7 = h4[(size_t)sB.w * 32 + base4];
    float d0 = dv[sA.x], d1 = dv[sA.y], d2 = dv[sA.z], d3 = dv[sA.w];
    float d4 = dv[sB.x], d5 = dv[sB.y], d6 = dv[sB.z], d7 = dv[sB.w];
    ax = fmaf(d0, bf2f(v0.x), ax); ay = fmaf(d0, bf2f(v0.y), ay); az = fmaf(d0, bf2f(v0.z), az); aw = fmaf(d0, bf2f(v0.w), aw);
    bx = fmaf(d1, bf2f(v1.x), bx); by = fmaf(d1, bf2f(v1.y), by); bz = fmaf(d1, bf2f(v1.z), bz); bw = fmaf(d1, bf2f(v1.w), bw);
    ax = fmaf(d2, bf2f(v2.x), ax); ay = fmaf(d2, bf2f(v2.y), ay); az = fmaf(d2, bf2f(v2.z), az); aw = fmaf(d2, bf2f(v2.w), aw);
    bx = fmaf(d3, bf2f(v3.x), bx); by = fmaf(d3, bf2f(v3.y), by); bz = fmaf(d3, bf2f(v3.z), bz); bw = fmaf(d3, bf2f(v3.w), bw);
    ax = fmaf(d4, bf2f(v4.x), ax); ay = fmaf(d4, bf2f(v4.y), ay); az = fmaf(d4, bf2f(v4.z), az); aw = fmaf(d4, bf2f(v4.w), aw);
    bx = fmaf(d5, bf2f(v5.x), bx); by = fmaf(d5, bf2f(v5.y), by); bz = fmaf(d5, bf2f(v5.z), bz); bw = fmaf(d5, bf2f(v5.w), bw);
    ax = fmaf(d6, bf2f(v6.x), ax); ay = fmaf(d6, bf2f(v6.y), ay); az = fmaf(d6, bf2f(v6.z), az); aw = fmaf(d6, bf2f(v6.w), aw);
    bx = fmaf(d7, bf2f(v7.x), bx); by = fmaf(d7, bf2f(v7.y), by); bz = fmaf(d7, bf2f(v7.z), bz); bw = fmaf(d7, bf2f(v7.w), bw);
  }
  ax += bx; ay += by; az += bz; aw += bw;
  float4 bb = ((const float4*)bias)[base4];
  float vx = fmaf(di, ax, bb.x), vy = fmaf(di, ay, bb.y);
  float vz = fmaf(di, az, bb.z), vw = fmaf(di, aw, bb.w);
  ushort4 hi4, lo4;
  hi4.x = f2bf(vx); lo4.x = f2bf(vx - bf2f(hi4.x));
  hi4.y = f2bf(vy); lo4.y = f2bf(vy - bf2f(hi4.y));
  hi4.z = f2bf(vz); lo4.z = f2bf(vz - bf2f(hi4.z));
  hi4.w = f2bf(vw); lo4.w = f2bf(vw - bf2f(hi4.w));
  ((ushort4*)outh)[(size_t)node * 32 + base4] = hi4;
  ((ushort4*)outl)[(size_t)node * 32 + base4] = lo4;
}

// ---------------- gemm2: A from hi/lo planes, 3-term, bf16 out ----------------

__global__ __launch_bounds__(256) void k_gemm_hl(const unsigned short* __restrict__ xh,
                                                 const unsigned short* __restrict__ xl,
                                                 const unsigned short* __restrict__ Wth,
                                                 const unsigned short* __restrict__ Wtl,
                                                 unsigned short* __restrict__ out, int nrows) {
  int wave = threadIdx.x >> 6, lane = threadIdx.x & 63;
  int l15 = lane & 15, quad = lane >> 4;
  int r0 = blockIdx.x * 128 + wave * 32;
  f32x4 acc[2][8];
  #pragma unroll
  for (int mt = 0; mt < 2; ++mt)
    #pragma unroll
    for (int nt = 0; nt < 8; ++nt) acc[mt][nt] = f32x4{0.f, 0.f, 0.f, 0.f};
  union U { uint4 u; bf16x8 h; };
  #pragma unroll
  for (int ks = 0; ks < 4; ++ks) {
    int k0 = ks * 32 + quad * 8;
    U ah[2], al[2];
    #pragma unroll
    for (int mt = 0; mt < 2; ++mt) {
      int row = r0 + mt * 16 + l15;
      row = (row < nrows) ? row : (nrows - 1);
      ah[mt].u = *(const uint4*)(xh + (size_t)row * DIM + k0);
      al[mt].u = *(const uint4*)(xl + (size_t)row * DIM + k0);
    }
    #pragma unroll
    for (int nt = 0; nt < 8; ++nt) {
      U bh, bl;
      bh.u = *(const uint4*)(Wth + (nt * 16 + l15) * DIM + k0);
      bl.u = *(const uint4*)(Wtl + (nt * 16 + l15) * DIM + k0);
      #pragma unroll
      for (int mt = 0; mt < 2; ++mt) {
        acc[mt][nt] = __builtin_amdgcn_mfma_f32_16x16x32_bf16(ah[mt].h, bh.h, acc[mt][nt], 0, 0, 0);
        acc[mt][nt] = __builtin_amdgcn_mfma_f32_16x16x32_bf16(al[mt].h, bh.h, acc[mt][nt], 0, 0, 0);
        acc[mt][nt] = __builtin_amdgcn_mfma_f32_16x16x32_bf16(ah[mt].h, bl.h, acc[mt][nt], 0, 0, 0);
      }
    }
  }
  #pragma unroll
  for (int mt = 0; mt < 2; ++mt)
    #pragma unroll
    for (int reg = 0; reg < 4; ++reg) {
      int row = r0 + mt * 16 + quad * 4 + reg;
      if (row < nrows) {
        #pragma unroll
        for (int nt = 0; nt < 8; ++nt)
          out[(size_t)row * DIM + nt * 16 + l15] = f2bf(acc[mt][nt][reg]);
      }
    }
}

// ---------------- full-row aggregation core (used by agg_batch only) ----------------

static __device__ __forceinline__ float4 agg_compute(const unsigned short* __restrict__ h,
                                                     const int* __restrict__ cnt,
                                                     const float* __restrict__ dv,
                                                     const int* __restrict__ esrc,
                                                     const float* __restrict__ bias,
                                                     int node, int lane) {
  const ushort4* h4 = (const ushort4*)h;
  int deg = cnt[node];
  int end = min((deg + 7) & ~7, CAP);              // padded length, multiple of 8
  float di = dv[node];
  ushort4 hv = h4[(size_t)node * 32 + lane];
  float ax = di * bf2f(hv.x), ay = di * bf2f(hv.y), az = di * bf2f(hv.z), aw = di * bf2f(hv.w);
  float bx = 0.f, by = 0.f, bz = 0.f, bw = 0.f;
  const int* eb = esrc + node * CAP;
  for (int e = 0; e < end; e += 8) {
    int4 sA = *(const int4*)(eb + e);
    int4 sB = *(const int4*)(eb + e + 4);
    ushort4 v0 = h4[(size_t)sA.x * 32 + lane];
    ushort4 v1 = h4[(size_t)sA.y * 32 + lane];
    ushort4 v2 = h4[(size_t)sA.z * 32 + lane];
    ushort4 v3 = h4[(size_t)sA.w * 32 + lane];
    ushort4 v4 = h4[(size_t)sB.x * 32 + lane];
    ushort4 v5 = h4[(size_t)sB.y * 32 + lane];
    ushort4 v6 = h4[(size_t)sB.z * 32 + lane];
    ushort4 v7 = h4[(size_t)sB.w * 32 + lane];
    float d0 = dv[sA.x], d1 = dv[sA.y], d2 = dv[sA.z], d3 = dv[sA.w];
    float d4 = dv[sB.x], d5 = dv[sB.y], d6 = dv[sB.z], d7 = dv[sB.w];
    ax = fmaf(d0, bf2f(v0.x), ax); ay = fmaf(d0, bf2f(v0.y), ay); az = fmaf(d0, bf2f(v0.z), az); aw = fmaf(d0, bf2f(v0.w), aw);
    bx = fmaf(d1, bf2f(v1.x), bx); by = fmaf(d1, bf2f(v1.y), by); bz = fmaf(d1, bf2f(v1.z), bz); bw = fmaf(d1, bf2f(v1.w), bw);
    ax = fmaf(d2, bf2f(v2.x), ax); ay = fmaf(d2, bf2f(v2.y), ay); az = fmaf(d2, bf2f(v2.z), az); aw = fmaf(d2, bf2f(v2.w), aw);
    bx = fmaf(d3, bf2f(v3.x), bx); by = fmaf(d3, bf2f(v3.y), by); bz = fmaf(d3, bf2f(v3.z), bz); bw = fmaf(d3, bf2f(v3.w), bw);
    ax = fmaf(d4, bf2f(v4.x), ax); ay = fmaf(d4, bf2f(v4.y), ay); az = fmaf(d4, bf2f(v4.z), az); aw = fmaf(d4, bf2f(v4.w), aw);
    bx = fmaf(d5, bf2f(v5.x), bx); by = fmaf(d5, bf2f(v5.y), by); bz = fmaf(d5, bf2f(v5.z), bz); bw = fmaf(d5, bf2f(v5.w), bw);
    ax = fmaf(d6, bf2f(v6.x), ax); ay = fmaf(d6, bf2f(v6.y), ay); az = fmaf(d6, bf2f(v6.z), az); aw = fmaf(d6, bf2f(v6.w), aw);
    bx = fmaf(d7, bf2f(v7.x), bx); by = fmaf(d7, bf2f(v7.y), by); bz = fmaf(d7, bf2f(v7.z), bz); bw = fmaf(d7, bf2f(v7.w), bw);
  }
  ax += bx; ay += by; az += bz; aw += bw;
  float4 bb = ((const float4*)bias)[lane];
  float4 v;
  v.x = fmaf(di, ax, bb.x); v.y = fmaf(di, ay, bb.y);
  v.z = fmaf(di, az, bb.z); v.w = fmaf(di, aw, bb.w);
  return v;
}

// ---------------- agg2 at batch positions only ----------------
// head rows -> fp32 plane pf[BATCH][128]; tail rows -> bf16 hi plane pth[BATCH][128]

__global__ __launch_bounds__(256) void k_agg_batch(const unsigned short* __restrict__ h,
                                                   const int* __restrict__ cnt,
                                                   const float* __restrict__ dv,
                                                   const int* __restrict__ esrc,
                                                   const float* __restrict__ bias,
                                                   const int* __restrict__ head,
                                                   const int* __restrict__ tail,
                                                   float* __restrict__ pf,
                                                   unsigned short* __restrict__ pth) {
  int pos = blockIdx.x * 8 + (threadIdx.x >> 5);
  if (pos >= 2 * BATCH) return;
  int lane = threadIdx.x & 31;
  int node = (pos < BATCH) ? head[pos] : tail[pos - BATCH];
  float4 v = agg_compute(h, cnt, dv, esrc, bias, node, lane);
  if (pos < BATCH) {
    ((float4*)pf)[(size_t)pos * 32 + lane] = v;
  } else {
    ushort4 hi4 = { f2bf(v.x), f2bf(v.y), f2bf(v.z), f2bf(v.w) };
    ((ushort4*)pth)[(size_t)(pos - BATCH) * 32 + lane] = hi4;
  }
}

// ---------------- predict via MFMA: tail (bf16) @ Q_r, dot with head (fp32) ----------------

__global__ __launch_bounds__(256) void k_predict_mfma(const float* __restrict__ pf,
                                                      const unsigned short* __restrict__ pth,
                                                      const unsigned short* __restrict__ Qbf,
                                                      float* __restrict__ out) {
  __shared__ __align__(16) unsigned short Qs[DIM * QPAD];
  int r = blockIdx.y;
  const unsigned short* Qr = Qbf + (size_t)r * DIM * DIM;
  for (int i = threadIdx.x; i < DIM * DIM / 8; i += 256) {
    int d = i >> 4, c = (i & 15) * 8;
    uint4 v = ((const uint4*)Qr)[i];
    *(uint4*)(&Qs[d * QPAD + c]) = v;
  }
  __syncthreads();
  int wave = threadIdx.x >> 6, lane = threadIdx.x & 63;
  int l15 = lane & 15, quad = lane >> 4;
  int bbase = blockIdx.x * 128 + wave * 32;
  int t0 = bbase + l15;                    // tail plane rows (coalesced, no gather)
  int t1 = bbase + 16 + l15;

  f32x4 acc[2][8];
  #pragma unroll
  for (int m = 0; m < 2; ++m)
    #pragma unroll
    for (int n = 0; n < 8; ++n) acc[m][n] = f32x4{0.f, 0.f, 0.f, 0.f};

  union U { uint4 u; bf16x8 h; };
  #pragma unroll
  for (int ks = 0; ks < 4; ++ks) {
    int eoff = ks * 32 + quad * 8;
    U a0, a1;
    a0.u = *(const uint4*)(pth + (size_t)t0 * DIM + eoff);
    a1.u = *(const uint4*)(pth + (size_t)t1 * DIM + eoff);
    #pragma unroll
    for (int nt = 0; nt < 8; ++nt) {
      U b; b.u = *(const uint4*)(&Qs[(nt * 16 + l15) * QPAD + eoff]);
      acc[0][nt] = __builtin_amdgcn_mfma_f32_16x16x32_bf16(a0.h, b.h, acc[0][nt], 0, 0, 0);
      acc[1][nt] = __builtin_amdgcn_mfma_f32_16x16x32_bf16(a1.h, b.h, acc[1][nt], 0, 0, 0);
    }
  }

  #pragma unroll
  for (int m = 0; m < 2; ++m) {
    #pragma unroll
    for (int reg = 0; reg < 4; ++reg) {
      int bl = bbase + m * 16 + quad * 4 + reg;             // batch index == head plane row
      float s = 0.f;
      #pragma unroll
      for (int nt = 0; nt < 8; ++nt)
        s += pf[(size_t)bl * DIM + nt * 16 + l15] * acc[m][nt][reg];   // head = fp32 plane
      #pragma unroll
      for (int off = 1; off < 16; off <<= 1) s += __shfl_xor(s, off, 64);
      if (l15 == 0) out[(size_t)bl * N_REL + r] = s;
    }
  }
}

// ---------------- launch ----------------

extern "C" void kernel_launch(void* const* d_in, const int* in_sizes, int n_in,
                              void* d_out, int out_size, void* d_ws, size_t ws_size,
                              hipStream_t stream) {
  (void)in_sizes; (void)n_in; (void)out_size; (void)ws_size;
  const float* init_emb = (const float*)d_in[0];
  const float* W1  = (const float*)d_in[1];
  const float* b1  = (const float*)d_in[2];
  const float* W2  = (const float*)d_in[3];
  const float* b2  = (const float*)d_in[4];
  const float* Rel = (const float*)d_in[5];
  const float* M   = (const float*)d_in[6];
  const int* head  = (const int*)d_in[7];
  const int* tail  = (const int*)d_in[8];
  const int* src   = (const int*)d_in[9];
  const int* dst   = src + N_EDGES;
  float* out = (float*)d_out;

  char* p = (char*)d_ws;
  auto alloc = [&](size_t bytes) { char* q = p; p += (bytes + 511) & ~(size_t)511; return q; };
  unsigned int* histBlk = (unsigned int*)alloc((size_t)EB * NP * 4);
  unsigned int* blkoff  = (unsigned int*)alloc((size_t)EB * NP * 4);
  unsigned int* partCnt = (unsigned int*)alloc((size_t)NP * 4);
  unsigned int* pe = (unsigned int*)alloc((size_t)NP * PCAP * 4);              // 6.4 MB packed edges
  int*   cnt = (int*)alloc((size_t)N_NODES * 4);
  float* dv  = (float*)alloc((size_t)(N_NODES + 1) * 4);                       // +1 sentinel
  int*   esrc = (int*)alloc((size_t)N_NODES * CAP * 4);                        // 12.8 MB buckets
  unsigned short* hbuf1 = (unsigned short*)alloc((size_t)(N_NODES + 1) * DIM * 2);  // +1 zero row
  unsigned short* hbuf2 = (unsigned short*)alloc((size_t)(N_NODES + 1) * DIM * 2);  // +1 zero row
  unsigned short* aggh  = (unsigned short*)alloc((size_t)N_NODES * DIM * 2);   // agg1 hi plane
  unsigned short* aggl  = (unsigned short*)alloc((size_t)N_NODES * DIM * 2);   // agg1 lo plane
  float*          pf    = (float*)alloc((size_t)BATCH * DIM * 4);              // head plane fp32
  unsigned short* pth   = (unsigned short*)alloc((size_t)BATCH * DIM * 2);     // tail plane bf16 hi
  unsigned short* Qbf   = (unsigned short*)alloc((size_t)N_REL * DIM * DIM * 2);
  unsigned short* W1th  = (unsigned short*)alloc((size_t)DIM * DIM * 2);
  unsigned short* W1tl  = (unsigned short*)alloc((size_t)DIM * DIM * 2);
  unsigned short* W2th  = (unsigned short*)alloc((size_t)DIM * DIM * 2);
  unsigned short* W2tl  = (unsigned short*)alloc((size_t)DIM * DIM * 2);
  unsigned short* Mth   = (unsigned short*)alloc((size_t)DIM * DIM * 2);

  // 0: weight prep + sentinel zeroing
  k_prep<<<DIM * DIM / 256, 256, 0, stream>>>(W1, W2, M, W1th, W1tl, W2th, W2tl, Mth,
                                              hbuf1, hbuf2, dv);
  // 1: per-block LDS histograms || decoder TQ
  k_histTQ<<<EB + G_TQ, 256, 0, stream>>>(dst, histBlk, Rel, Mth, Qbf);
  // 2: per-bin cross-block scan -> absolute offsets
  k_scanB<<<NP, 256, 0, stream>>>(histBlk, blkoff, partCnt);
  // 3: scatter packed edges to partitions (LDS slotting) || gemm1
  k_scatG<<<EB + G_GEMM, 256, 0, stream>>>(src, dst, blkoff, pe, init_emb, W1th, W1tl, hbuf1);
  // 4: per-partition bucket fill (pad-to-8) -> esrc + cnt + dinv
  k_build<<<NP, 256, 0, stream>>>(pe, partCnt, esrc, cnt, dv);
  // 5: agg1 by dim-slab (XCD-L2-resident working set) -> hi/lo planes
  k_agg_slab<<<SLAB_GRID, 256, 0, stream>>>(hbuf1, cnt, dv, esrc, b1, aggh, aggl);
  // 6: gemm2 from planes
  k_gemm_hl<<<(N_NODES + 127) / 128, 256, 0, stream>>>(aggh, aggl, W2th, W2tl, hbuf2, N_NODES);
  // 7: agg2 only at batch positions -> compact planes (head fp32, tail bf16)
  k_agg_batch<<<(2 * BATCH + 7) / 8, 256, 0, stream>>>(hbuf2, cnt, dv, esrc, b2, head, tail, pf, pth);
  // 8: predict (coalesced reads from compact planes)
  k_predict_mfma<<<dim3(BATCH / 128, N_REL), 256, 0, stream>>>(pf, pth, Qbf, out);
}

// Round 7
// 232.275 us; speedup vs baseline: 1.0400x; 1.0400x over previous
//
#include <hip/hip_runtime.h>

#define N_NODES 50000
#define N_EDGES 800000
#define DIM 128
#define N_REL 86
#define BATCH 2048
#define CAP 64               // per-node bucket capacity; max deg ~45 for Poisson(16)
#define ZROW N_NODES         // sentinel row: zeroed embedding row, dv[ZROW]=0 (fits u16)

#define NP 196               // partitions by dst>>8 (256 nodes each; ceil(50000/256))
#define EB 196               // edge blocks for hist/scatter (4096 edges each)
#define PCAP 8192            // partition edge capacity (mean 4096, sigma 64)

#define NSLAB 4              // 32-dim slabs; slab-major planes: 3.2 MB each, L2-resident
#define PSTR ((size_t)(N_NODES + 1) * 32)                       // ushorts per slab plane
#define NODES_PER_BLK 32     // 256 threads / 8 lanes per node
#define NBLK ((N_NODES + NODES_PER_BLK - 1) / NODES_PER_BLK)    // 1563
#define SLAB_GRID (8 * ((NBLK + 1) / 2))                        // 6256

using bf16x8 = __attribute__((ext_vector_type(8))) short;
using f32x4  = __attribute__((ext_vector_type(4))) float;

// float -> bf16 round-to-nearest-even (finite inputs)
static __device__ __forceinline__ unsigned short f2bf(float f) {
  union { float f; unsigned int i; } v; v.f = f;
  unsigned int x = v.i;
  unsigned int r = x + 0x7FFFu + ((x >> 16) & 1u);
  return (unsigned short)(r >> 16);
}
static __device__ __forceinline__ float bf2f(unsigned short u) {
  union { unsigned int i; float f; } v;
  v.i = ((unsigned int)u) << 16;
  return v.f;
}

#define G_TQ    172           // 86 relations x 2 d-blocks
#define G_GEMM  391           // ceil(50000/128)
#define TPAD 136              // 128+8 bf16: 272 B row stride -> 2-way bank alias (free)
#define QPAD 136

// ---------------- kernel 0: weight prep + sentinel-row zeroing ----------------

__global__ __launch_bounds__(256) void k_prep(const float* __restrict__ W1, const float* __restrict__ W2,
                                              const float* __restrict__ M,
                                              unsigned short* __restrict__ W1th, unsigned short* __restrict__ W1tl,
                                              unsigned short* __restrict__ W2th, unsigned short* __restrict__ W2tl,
                                              unsigned short* __restrict__ Mth,
                                              unsigned short* __restrict__ hs,
                                              unsigned short* __restrict__ hbuf2,
                                              float* __restrict__ dv) {
  int g = blockIdx.x * 256 + threadIdx.x;          // 16384 threads = DIM*DIM
  // zero sentinel rows (gather pads resolve to ZROW; must be 0.0 not garbage/NaN)
  if (g < 32) {                                    // 4 slab planes x 8 ushort4
    ushort4 z = {0, 0, 0, 0};
    ((ushort4*)(hs + (size_t)(g >> 3) * PSTR))[(size_t)ZROW * 8 + (g & 7)] = z;
  } else if (g < 64) {                             // hbuf2 row (32 ushort4)
    ushort4 z = {0, 0, 0, 0};
    ((ushort4*)hbuf2)[(size_t)ZROW * 32 + (g - 32)] = z;
  } else if (g == 64) {
    dv[ZROW] = 0.f;
  }
  int k = g >> 7, n = g & 127;
  int t = n * DIM + k;
  float w1 = W1[g];
  unsigned short h1 = f2bf(w1);
  W1th[t] = h1;
  W1tl[t] = f2bf(w1 - bf2f(h1));
  float w2 = W2[g];
  unsigned short h2 = f2bf(w2);
  W2th[t] = h2;
  W2tl[t] = f2bf(w2 - bf2f(h2));
  Mth[t] = f2bf(M[g]);
}

// ---------------- build pass 1: per-block LDS histogram over dst>>8  ||  decoder TQ ----------------

__global__ __launch_bounds__(256) void k_histTQ(const int* __restrict__ dst,
                                                unsigned int* __restrict__ histBlk,
                                                const float* __restrict__ Rel,
                                                const unsigned short* __restrict__ Mth,
                                                unsigned short* __restrict__ Qbf) {
  __shared__ __align__(16) unsigned char smem[64 * TPAD * 2];   // max(hist 784B, Ts 17408B)
  int bid = blockIdx.x;
  union U { uint4 u; bf16x8 h; };

  if (bid < EB) {
    unsigned int* hist = (unsigned int*)smem;
    int t = threadIdx.x;
    if (t < NP) hist[t] = 0u;
    __syncthreads();
    #pragma unroll
    for (int j = 0; j < 4; ++j) {
      int i0 = bid * 4096 + j * 1024 + t * 4;
      if (i0 < N_EDGES) {
        int4 d4 = *(const int4*)(dst + i0);
        atomicAdd(&hist[d4.x >> 8], 1u);
        atomicAdd(&hist[d4.y >> 8], 1u);
        atomicAdd(&hist[d4.z >> 8], 1u);
        atomicAdd(&hist[d4.w >> 8], 1u);
      }
    }
    __syncthreads();
    if (t < NP) histBlk[bid * NP + t] = hist[t];
    return;
  }

  // ---- decoder precompute: T_r = Rel_r @ M (LDS), Q_r = T_r @ Rel_r^T ----
  unsigned short* Ts = (unsigned short*)smem;
  int wave = threadIdx.x >> 6, lane = threadIdx.x & 63;
  int l15 = lane & 15, quad = lane >> 4;
  int tb = bid - EB;                       // [0, 172)
  int r = tb >> 1, dblk = tb & 1;
  const float* Rr = Rel + (size_t)r * DIM * DIM;
  unsigned short* Qr = Qbf + (size_t)r * DIM * DIM;
  int dw = dblk * 64 + wave * 16;
  f32x4 acc[8];
  #pragma unroll
  for (int nt = 0; nt < 8; ++nt) acc[nt] = f32x4{0.f, 0.f, 0.f, 0.f};
  #pragma unroll
  for (int ks = 0; ks < 4; ++ks) {
    int k0 = ks * 32 + quad * 8;
    const float* ap = Rr + (size_t)(dw + l15) * DIM + k0;
    float av[8];
    *(float4*)(av)     = *(const float4*)(ap);
    *(float4*)(av + 4) = *(const float4*)(ap + 4);
    bf16x8 a;
    #pragma unroll
    for (int j = 0; j < 8; ++j) a[j] = (short)f2bf(av[j]);
    #pragma unroll
    for (int nt = 0; nt < 8; ++nt) {
      U b; b.u = *(const uint4*)(Mth + (nt * 16 + l15) * DIM + k0);
      acc[nt] = __builtin_amdgcn_mfma_f32_16x16x32_bf16(a, b.h, acc[nt], 0, 0, 0);
    }
  }
  #pragma unroll
  for (int nt = 0; nt < 8; ++nt)
    #pragma unroll
    for (int reg = 0; reg < 4; ++reg)
      Ts[(wave * 16 + quad * 4 + reg) * TPAD + nt * 16 + l15] = f2bf(acc[nt][reg]);
  __syncthreads();
  f32x4 qacc[8];
  #pragma unroll
  for (int nt = 0; nt < 8; ++nt) qacc[nt] = f32x4{0.f, 0.f, 0.f, 0.f};
  #pragma unroll
  for (int ks = 0; ks < 4; ++ks) {
    int k0 = ks * 32 + quad * 8;
    U a; a.u = *(const uint4*)(Ts + (wave * 16 + l15) * TPAD + k0);
    #pragma unroll
    for (int nt = 0; nt < 8; ++nt) {
      const float* bp = Rr + (size_t)(nt * 16 + l15) * DIM + k0;
      float bv[8];
      *(float4*)(bv)     = *(const float4*)(bp);
      *(float4*)(bv + 4) = *(const float4*)(bp + 4);
      bf16x8 b;
      #pragma unroll
      for (int j = 0; j < 8; ++j) b[j] = (short)f2bf(bv[j]);
      qacc[nt] = __builtin_amdgcn_mfma_f32_16x16x32_bf16(a.h, b, qacc[nt], 0, 0, 0);
    }
  }
  #pragma unroll
  for (int nt = 0; nt < 8; ++nt)
    #pragma unroll
    for (int reg = 0; reg < 4; ++reg)
      Qr[(size_t)(dw + quad * 4 + reg) * DIM + nt * 16 + l15] = f2bf(qacc[nt][reg]);
}

// ---------------- build pass 2: per-bin cross-block exclusive scan ----------------

__global__ __launch_bounds__(256) void k_scanB(const unsigned int* __restrict__ histBlk,
                                               unsigned int* __restrict__ blkoff,
                                               unsigned int* __restrict__ partCnt) {
  __shared__ unsigned int sd[256];
  int b = blockIdx.x;          // bin
  int t = threadIdx.x;
  unsigned int v = (t < EB) ? histBlk[t * NP + b] : 0u;
  sd[t] = v; __syncthreads();
  for (int off = 1; off < 256; off <<= 1) {
    unsigned int y = (t >= off) ? sd[t - off] : 0u;
    __syncthreads();
    sd[t] += y;
    __syncthreads();
  }
  if (t < EB) blkoff[t * NP + b] = (unsigned int)b * PCAP + sd[t] - v;
  if (t == EB - 1) partCnt[b] = sd[t];
}

// ---------------- build pass 3: scatter packed edges to partitions (LDS slotting)  ||  gemm1 ----------------
// pe entry: (dst & 255) << 17 | src     (src < 50000 < 2^17)
// gemm1 writes hbuf1 in SLAB-MAJOR planes: hs[slab][(node)*32 + d], d in [0,32)

__global__ __launch_bounds__(256) void k_scatG(const int* __restrict__ src, const int* __restrict__ dst,
                                               const unsigned int* __restrict__ blkoff,
                                               unsigned int* __restrict__ pe,
                                               const float* __restrict__ x,
                                               const unsigned short* __restrict__ W1th,
                                               const unsigned short* __restrict__ W1tl,
                                               unsigned short* __restrict__ hs) {
  __shared__ unsigned int lcnt[NP];
  int bid = blockIdx.x;
  union U { uint4 u; bf16x8 h; };

  if (bid < EB) {
    int t = threadIdx.x;
    if (t < NP) lcnt[t] = blkoff[bid * NP + t];
    __syncthreads();
    #pragma unroll
    for (int j = 0; j < 4; ++j) {
      int i0 = bid * 4096 + j * 1024 + t * 4;
      if (i0 < N_EDGES) {
        int4 s4 = *(const int4*)(src + i0);
        int4 d4 = *(const int4*)(dst + i0);
        int b0 = d4.x >> 8, b1 = d4.y >> 8, b2 = d4.z >> 8, b3 = d4.w >> 8;
        unsigned int p0 = atomicAdd(&lcnt[b0], 1u);
        unsigned int p1 = atomicAdd(&lcnt[b1], 1u);
        unsigned int p2 = atomicAdd(&lcnt[b2], 1u);
        unsigned int p3 = atomicAdd(&lcnt[b3], 1u);
        if (p0 < (unsigned int)(b0 + 1) * PCAP) pe[p0] = ((unsigned)(d4.x & 255) << 17) | (unsigned)s4.x;
        if (p1 < (unsigned int)(b1 + 1) * PCAP) pe[p1] = ((unsigned)(d4.y & 255) << 17) | (unsigned)s4.y;
        if (p2 < (unsigned int)(b2 + 1) * PCAP) pe[p2] = ((unsigned)(d4.z & 255) << 17) | (unsigned)s4.z;
        if (p3 < (unsigned int)(b3 + 1) * PCAP) pe[p3] = ((unsigned)(d4.w & 255) << 17) | (unsigned)s4.w;
      }
    }
    return;
  }

  // ---- node GEMM layer 1: hs = slab-major(x @ W1) (hi/lo 3-term, bf16 out) ----
  int wave = threadIdx.x >> 6, lane = threadIdx.x & 63;
  int l15 = lane & 15, quad = lane >> 4;
  int r0 = (bid - EB) * 128 + wave * 32;
  f32x4 acc[2][8];
  #pragma unroll
  for (int mt = 0; mt < 2; ++mt)
    #pragma unroll
    for (int nt = 0; nt < 8; ++nt) acc[mt][nt] = f32x4{0.f, 0.f, 0.f, 0.f};
  #pragma unroll
  for (int ks = 0; ks < 4; ++ks) {
    int k0 = ks * 32 + quad * 8;
    bf16x8 ah[2], al[2];
    #pragma unroll
    for (int mt = 0; mt < 2; ++mt) {
      int row = r0 + mt * 16 + l15;
      row = (row < N_NODES) ? row : (N_NODES - 1);
      const float* xp = x + (size_t)row * DIM + k0;
      float xv[8];
      *(float4*)(xv)     = *(const float4*)(xp);
      *(float4*)(xv + 4) = *(const float4*)(xp + 4);
      #pragma unroll
      for (int j = 0; j < 8; ++j) {
        unsigned short h = f2bf(xv[j]);
        ah[mt][j] = (short)h;
        al[mt][j] = (short)f2bf(xv[j] - bf2f(h));
      }
    }
    #pragma unroll
    for (int nt = 0; nt < 8; ++nt) {
      U bh, bl;
      bh.u = *(const uint4*)(W1th + (nt * 16 + l15) * DIM + k0);
      bl.u = *(const uint4*)(W1tl + (nt * 16 + l15) * DIM + k0);
      #pragma unroll
      for (int mt = 0; mt < 2; ++mt) {
        acc[mt][nt] = __builtin_amdgcn_mfma_f32_16x16x32_bf16(ah[mt], bh.h, acc[mt][nt], 0, 0, 0);
        acc[mt][nt] = __builtin_amdgcn_mfma_f32_16x16x32_bf16(al[mt], bh.h, acc[mt][nt], 0, 0, 0);
        acc[mt][nt] = __builtin_amdgcn_mfma_f32_16x16x32_bf16(ah[mt], bl.h, acc[mt][nt], 0, 0, 0);
      }
    }
  }
  #pragma unroll
  for (int mt = 0; mt < 2; ++mt)
    #pragma unroll
    for (int reg = 0; reg < 4; ++reg) {
      int row = r0 + mt * 16 + quad * 4 + reg;
      if (row < N_NODES) {
        #pragma unroll
        for (int nt = 0; nt < 8; ++nt)
          hs[(size_t)(nt >> 1) * PSTR + (size_t)row * 32 + (nt & 1) * 16 + l15] = f2bf(acc[mt][nt][reg]);
      }
    }
}

// ---------------- build pass 4: per-partition bucket fill (u16) + pad-to-8 + cnt + dinv ----------------

__global__ __launch_bounds__(256) void k_build(const unsigned int* __restrict__ pe,
                                               const unsigned int* __restrict__ partCnt,
                                               unsigned short* __restrict__ esrc, int* __restrict__ cnt,
                                               float* __restrict__ dv) {
  __shared__ unsigned int c256[256];
  int p = blockIdx.x, t = threadIdx.x;
  c256[t] = 0u;
  __syncthreads();
  int m = min((int)partCnt[p], PCAP);
  for (int i = t; i < m; i += 256) {
    unsigned int e = pe[(size_t)p * PCAP + i];
    unsigned int local = e >> 17;
    unsigned int s = e & 0x1FFFFu;
    unsigned int slot = atomicAdd(&c256[local], 1u);
    int node = p * 256 + (int)local;
    if (slot < CAP) esrc[(size_t)node * CAP + slot] = (unsigned short)s;
  }
  __syncthreads();
  int node = p * 256 + t;
  if (node < N_NODES) {
    int c = (int)c256[t];
    cnt[node] = c;
    dv[node] = rsqrtf((float)(c + 1));
    int padded = min((c + 7) & ~7, CAP);          // pad bucket to multiple of 8
    for (int s = c; s < padded; ++s) esrc[(size_t)node * CAP + s] = (unsigned short)ZROW;
  }
}

// ---------------- agg1 by dim-slab over SLAB-MAJOR planes ----------------
// plane s = hs + s*PSTR: 3.2 MB contiguous, line-aligned 64 B row-slabs -> L2-resident.
// bid%8 -> XCD (round-robin heuristic, perf-only): slab = (bid&7)>>1, each slab on 2 XCDs.
// 8 lanes per node: lane loads ushort4 (8B); group covers the full 64 B row-slab.

__global__ __launch_bounds__(256) void k_agg_slab(const unsigned short* __restrict__ hs,
                                                  const int* __restrict__ cnt,
                                                  const float* __restrict__ dv,
                                                  const unsigned short* __restrict__ esrc,
                                                  const float* __restrict__ bias,
                                                  unsigned short* __restrict__ outh,
                                                  unsigned short* __restrict__ outl) {
  int bid = blockIdx.x;
  int slab = (bid & 7) >> 1;
  int nb = (bid >> 3) * 2 + (bid & 1);
  if (nb >= NBLK) return;
  int grp = threadIdx.x >> 3, lane8 = threadIdx.x & 7;
  int node = nb * NODES_PER_BLK + grp;
  if (node >= N_NODES) return;

  const ushort4* h4 = (const ushort4*)(hs + (size_t)slab * PSTR);   // 8 x ushort4 per row-slab
  int deg = cnt[node];
  int end = min((deg + 7) & ~7, CAP);             // padded multiple of 8
  float di = dv[node];
  ushort4 hv = h4[(size_t)node * 8 + lane8];
  float ax = di * bf2f(hv.x), ay = di * bf2f(hv.y), az = di * bf2f(hv.z), aw = di * bf2f(hv.w);
  float bx = 0.f, by = 0.f, bz = 0.f, bw = 0.f;
  const unsigned short* eb = esrc + (size_t)node * CAP;
  for (int e = 0; e < end; e += 8) {
    ushort4 iA = *(const ushort4*)(eb + e);       // 8 u16 indices (16 B, aligned)
    ushort4 iB = *(const ushort4*)(eb + e + 4);
    ushort4 v0 = h4[(size_t)iA.x * 8 + lane8];
    ushort4 v1 = h4[(size_t)iA.y * 8 + lane8];
    ushort4 v2 = h4[(size_t)iA.z * 8 + lane8];
    ushort4 v3 = h4[(size_t)iA.w * 8 + lane8];
    ushort4 v4 = h4[(size_t)iB.x * 8 + lane8];
    ushort4 v5 = h4[(size_t)iB.y * 8 + lane8];
    ushort4 v6 = h4[(size_t)iB.z * 8 + lane8];
    ushort4 v7 = h4[(size_t)iB.w * 8 + lane8];
    float d0 = dv[iA.x], d1 = dv[iA.y], d2 = dv[iA.z], d3 = dv[iA.w];
    float d4 = dv[iB.x], d5 = dv[iB.y], d6 = dv[iB.z], d7 = dv[iB.w];
    ax = fmaf(d0, bf2f(v0.x), ax); ay = fmaf(d0, bf2f(v0.y), ay); az = fmaf(d0, bf2f(v0.z), az); aw = fmaf(d0, bf2f(v0.w), aw);
    bx = fmaf(d1, bf2f(v1.x), bx); by = fmaf(d1, bf2f(v1.y), by); bz = fmaf(d1, bf2f(v1.z), bz); bw = fmaf(d1, bf2f(v1.w), bw);
    ax = fmaf(d2, bf2f(v2.x), ax); ay = fmaf(d2, bf2f(v2.y), ay); az = fmaf(d2, bf2f(v2.z), az); aw = fmaf(d2, bf2f(v2.w), aw);
    bx = fmaf(d3, bf2f(v3.x), bx); by = fmaf(d3, bf2f(v3.y), by); bz = fmaf(d3, bf2f(v3.z), bz); bw = fmaf(d3, bf2f(v3.w), bw);
    ax = fmaf(d4, bf2f(v4.x), ax); ay = fmaf(d4, bf2f(v4.y), ay); az = fmaf(d4, bf2f(v4.z), az); aw = fmaf(d4, bf2f(v4.w), aw);
    bx = fmaf(d5, bf2f(v5.x), bx); by = fmaf(d5, bf2f(v5.y), by); bz = fmaf(d5, bf2f(v5.z), bz); bw = fmaf(d5, bf2f(v5.w), bw);
    ax = fmaf(d6, bf2f(v6.x), ax); ay = fmaf(d6, bf2f(v6.y), ay); az = fmaf(d6, bf2f(v6.z), az); aw = fmaf(d6, bf2f(v6.w), aw);
    bx = fmaf(d7, bf2f(v7.x), bx); by = fmaf(d7, bf2f(v7.y), by); bz = fmaf(d7, bf2f(v7.z), bz); bw = fmaf(d7, bf2f(v7.w), bw);
  }
  ax += bx; ay += by; az += bz; aw += bw;
  int base4 = slab * 8 + lane8;
  float4 bb = ((const float4*)bias)[base4];
  float vx = fmaf(di, ax, bb.x), vy = fmaf(di, ay, bb.y);
  float vz = fmaf(di, az, bb.z), vw = fmaf(di, aw, bb.w);
  ushort4 hi4, lo4;
  hi4.x = f2bf(vx); lo4.x = f2bf(vx - bf2f(hi4.x));
  hi4.y = f2bf(vy); lo4.y = f2bf(vy - bf2f(hi4.y));
  hi4.z = f2bf(vz); lo4.z = f2bf(vz - bf2f(hi4.z));
  hi4.w = f2bf(vw); lo4.w = f2bf(vw - bf2f(hi4.w));
  ((ushort4*)outh)[(size_t)node * 32 + base4] = hi4;
  ((ushort4*)outl)[(size_t)node * 32 + base4] = lo4;
}

// ---------------- gemm2: A from hi/lo planes, 3-term, bf16 out (row-major) ----------------

__global__ __launch_bounds__(256) void k_gemm_hl(const unsigned short* __restrict__ xh,
                                                 const unsigned short* __restrict__ xl,
                                                 const unsigned short* __restrict__ Wth,
                                                 const unsigned short* __restrict__ Wtl,
                                                 unsigned short* __restrict__ out, int nrows) {
  int wave = threadIdx.x >> 6, lane = threadIdx.x & 63;
  int l15 = lane & 15, quad = lane >> 4;
  int r0 = blockIdx.x * 128 + wave * 32;
  f32x4 acc[2][8];
  #pragma unroll
  for (int mt = 0; mt < 2; ++mt)
    #pragma unroll
    for (int nt = 0; nt < 8; ++nt) acc[mt][nt] = f32x4{0.f, 0.f, 0.f, 0.f};
  union U { uint4 u; bf16x8 h; };
  #pragma unroll
  for (int ks = 0; ks < 4; ++ks) {
    int k0 = ks * 32 + quad * 8;
    U ah[2], al[2];
    #pragma unroll
    for (int mt = 0; mt < 2; ++mt) {
      int row = r0 + mt * 16 + l15;
      row = (row < nrows) ? row : (nrows - 1);
      ah[mt].u = *(const uint4*)(xh + (size_t)row * DIM + k0);
      al[mt].u = *(const uint4*)(xl + (size_t)row * DIM + k0);
    }
    #pragma unroll
    for (int nt = 0; nt < 8; ++nt) {
      U bh, bl;
      bh.u = *(const uint4*)(Wth + (nt * 16 + l15) * DIM + k0);
      bl.u = *(const uint4*)(Wtl + (nt * 16 + l15) * DIM + k0);
      #pragma unroll
      for (int mt = 0; mt < 2; ++mt) {
        acc[mt][nt] = __builtin_amdgcn_mfma_f32_16x16x32_bf16(ah[mt].h, bh.h, acc[mt][nt], 0, 0, 0);
        acc[mt][nt] = __builtin_amdgcn_mfma_f32_16x16x32_bf16(al[mt].h, bh.h, acc[mt][nt], 0, 0, 0);
        acc[mt][nt] = __builtin_amdgcn_mfma_f32_16x16x32_bf16(ah[mt].h, bl.h, acc[mt][nt], 0, 0, 0);
      }
    }
  }
  #pragma unroll
  for (int mt = 0; mt < 2; ++mt)
    #pragma unroll
    for (int reg = 0; reg < 4; ++reg) {
      int row = r0 + mt * 16 + quad * 4 + reg;
      if (row < nrows) {
        #pragma unroll
        for (int nt = 0; nt < 8; ++nt)
          out[(size_t)row * DIM + nt * 16 + l15] = f2bf(acc[mt][nt][reg]);
      }
    }
}

// ---------------- full-row aggregation core (used by agg_batch only; hbuf2 row-major) ----------------

static __device__ __forceinline__ float4 agg_compute(const unsigned short* __restrict__ h,
                                                     const int* __restrict__ cnt,
                                                     const float* __restrict__ dv,
                                                     const unsigned short* __restrict__ esrc,
                                                     const float* __restrict__ bias,
                                                     int node, int lane) {
  const ushort4* h4 = (const ushort4*)h;
  int deg = cnt[node];
  int end = min((deg + 7) & ~7, CAP);              // padded length, multiple of 8
  float di = dv[node];
  ushort4 hv = h4[(size_t)node * 32 + lane];
  float ax = di * bf2f(hv.x), ay = di * bf2f(hv.y), az = di * bf2f(hv.z), aw = di * bf2f(hv.w);
  float bx = 0.f, by = 0.f, bz = 0.f, bw = 0.f;
  const unsigned short* eb = esrc + (size_t)node * CAP;
  for (int e = 0; e < end; e += 8) {
    ushort4 iA = *(const ushort4*)(eb + e);
    ushort4 iB = *(const ushort4*)(eb + e + 4);
    ushort4 v0 = h4[(size_t)iA.x * 32 + lane];
    ushort4 v1 = h4[(size_t)iA.y * 32 + lane];
    ushort4 v2 = h4[(size_t)iA.z * 32 + lane];
    ushort4 v3 = h4[(size_t)iA.w * 32 + lane];
    ushort4 v4 = h4[(size_t)iB.x * 32 + lane];
    ushort4 v5 = h4[(size_t)iB.y * 32 + lane];
    ushort4 v6 = h4[(size_t)iB.z * 32 + lane];
    ushort4 v7 = h4[(size_t)iB.w * 32 + lane];
    float d0 = dv[iA.x], d1 = dv[iA.y], d2 = dv[iA.z], d3 = dv[iA.w];
    float d4 = dv[iB.x], d5 = dv[iB.y], d6 = dv[iB.z], d7 = dv[iB.w];
    ax = fmaf(d0, bf2f(v0.x), ax); ay = fmaf(d0, bf2f(v0.y), ay); az = fmaf(d0, bf2f(v0.z), az); aw = fmaf(d0, bf2f(v0.w), aw);
    bx = fmaf(d1, bf2f(v1.x), bx); by = fmaf(d1, bf2f(v1.y), by); bz = fmaf(d1, bf2f(v1.z), bz); bw = fmaf(d1, bf2f(v1.w), bw);
    ax = fmaf(d2, bf2f(v2.x), ax); ay = fmaf(d2, bf2f(v2.y), ay); az = fmaf(d2, bf2f(v2.z), az); aw = fmaf(d2, bf2f(v2.w), aw);
    bx = fmaf(d3, bf2f(v3.x), bx); by = fmaf(d3, bf2f(v3.y), by); bz = fmaf(d3, bf2f(v3.z), bz); bw = fmaf(d3, bf2f(v3.w), bw);
    ax = fmaf(d4, bf2f(v4.x), ax); ay = fmaf(d4, bf2f(v4.y), ay); az = fmaf(d4, bf2f(v4.z), az); aw = fmaf(d4, bf2f(v4.w), aw);
    bx = fmaf(d5, bf2f(v5.x), bx); by = fmaf(d5, bf2f(v5.y), by); bz = fmaf(d5, bf2f(v5.z), bz); bw = fmaf(d5, bf2f(v5.w), bw);
    ax = fmaf(d6, bf2f(v6.x), ax); ay = fmaf(d6, bf2f(v6.y), ay); az = fmaf(d6, bf2f(v6.z), az); aw = fmaf(d6, bf2f(v6.w), aw);
    bx = fmaf(d7, bf2f(v7.x), bx); by = fmaf(d7, bf2f(v7.y), by); bz = fmaf(d7, bf2f(v7.z), bz); bw = fmaf(d7, bf2f(v7.w), bw);
  }
  ax += bx; ay += by; az += bz; aw += bw;
  float4 bb = ((const float4*)bias)[lane];
  float4 v;
  v.x = fmaf(di, ax, bb.x); v.y = fmaf(di, ay, bb.y);
  v.z = fmaf(di, az, bb.z); v.w = fmaf(di, aw, bb.w);
  return v;
}

// ---------------- agg2 at batch positions only ----------------
// head rows -> fp32 plane pf[BATCH][128]; tail rows -> bf16 hi plane pth[BATCH][128]

__global__ __launch_bounds__(256) void k_agg_batch(const unsigned short* __restrict__ h,
                                                   const int* __restrict__ cnt,
                                                   const float* __restrict__ dv,
                                                   const unsigned short* __restrict__ esrc,
                                                   const float* __restrict__ bias,
                                                   const int* __restrict__ head,
                                                   const int* __restrict__ tail,
                                                   float* __restrict__ pf,
                                                   unsigned short* __restrict__ pth) {
  int pos = blockIdx.x * 8 + (threadIdx.x >> 5);
  if (pos >= 2 * BATCH) return;
  int lane = threadIdx.x & 31;
  int node = (pos < BATCH) ? head[pos] : tail[pos - BATCH];
  float4 v = agg_compute(h, cnt, dv, esrc, bias, node, lane);
  if (pos < BATCH) {
    ((float4*)pf)[(size_t)pos * 32 + lane] = v;
  } else {
    ushort4 hi4 = { f2bf(v.x), f2bf(v.y), f2bf(v.z), f2bf(v.w) };
    ((ushort4*)pth)[(size_t)(pos - BATCH) * 32 + lane] = hi4;
  }
}

// ---------------- predict via MFMA: tail (bf16) @ Q_r, dot with head (fp32) ----------------

__global__ __launch_bounds__(256) void k_predict_mfma(const float* __restrict__ pf,
                                                      const unsigned short* __restrict__ pth,
                                                      const unsigned short* __restrict__ Qbf,
                                                      float* __restrict__ out) {
  __shared__ __align__(16) unsigned short Qs[DIM * QPAD];
  int r = blockIdx.y;
  const unsigned short* Qr = Qbf + (size_t)r * DIM * DIM;
  for (int i = threadIdx.x; i < DIM * DIM / 8; i += 256) {
    int d = i >> 4, c = (i & 15) * 8;
    uint4 v = ((const uint4*)Qr)[i];
    *(uint4*)(&Qs[d * QPAD + c]) = v;
  }
  __syncthreads();
  int wave = threadIdx.x >> 6, lane = threadIdx.x & 63;
  int l15 = lane & 15, quad = lane >> 4;
  int bbase = blockIdx.x * 128 + wave * 32;
  int t0 = bbase + l15;                    // tail plane rows (coalesced, no gather)
  int t1 = bbase + 16 + l15;

  f32x4 acc[2][8];
  #pragma unroll
  for (int m = 0; m < 2; ++m)
    #pragma unroll
    for (int n = 0; n < 8; ++n) acc[m][n] = f32x4{0.f, 0.f, 0.f, 0.f};

  union U { uint4 u; bf16x8 h; };
  #pragma unroll
  for (int ks = 0; ks < 4; ++ks) {
    int eoff = ks * 32 + quad * 8;
    U a0, a1;
    a0.u = *(const uint4*)(pth + (size_t)t0 * DIM + eoff);
    a1.u = *(const uint4*)(pth + (size_t)t1 * DIM + eoff);
    #pragma unroll
    for (int nt = 0; nt < 8; ++nt) {
      U b; b.u = *(const uint4*)(&Qs[(nt * 16 + l15) * QPAD + eoff]);
      acc[0][nt] = __builtin_amdgcn_mfma_f32_16x16x32_bf16(a0.h, b.h, acc[0][nt], 0, 0, 0);
      acc[1][nt] = __builtin_amdgcn_mfma_f32_16x16x32_bf16(a1.h, b.h, acc[1][nt], 0, 0, 0);
    }
  }

  #pragma unroll
  for (int m = 0; m < 2; ++m) {
    #pragma unroll
    for (int reg = 0; reg < 4; ++reg) {
      int bl = bbase + m * 16 + quad * 4 + reg;             // batch index == head plane row
      float s = 0.f;
      #pragma unroll
      for (int nt = 0; nt < 8; ++nt)
        s += pf[(size_t)bl * DIM + nt * 16 + l15] * acc[m][nt][reg];   // head = fp32 plane
      #pragma unroll
      for (int off = 1; off < 16; off <<= 1) s += __shfl_xor(s, off, 64);
      if (l15 == 0) out[(size_t)bl * N_REL + r] = s;
    }
  }
}

// ---------------- launch ----------------

extern "C" void kernel_launch(void* const* d_in, const int* in_sizes, int n_in,
                              void* d_out, int out_size, void* d_ws, size_t ws_size,
                              hipStream_t stream) {
  (void)in_sizes; (void)n_in; (void)out_size; (void)ws_size;
  const float* init_emb = (const float*)d_in[0];
  const float* W1  = (const float*)d_in[1];
  const float* b1  = (const float*)d_in[2];
  const float* W2  = (const float*)d_in[3];
  const float* b2  = (const float*)d_in[4];
  const float* Rel = (const float*)d_in[5];
  const float* M   = (const float*)d_in[6];
  const int* head  = (const int*)d_in[7];
  const int* tail  = (const int*)d_in[8];
  const int* src   = (const int*)d_in[9];
  const int* dst   = src + N_EDGES;
  float* out = (float*)d_out;

  char* p = (char*)d_ws;
  auto alloc = [&](size_t bytes) { char* q = p; p += (bytes + 511) & ~(size_t)511; return q; };
  unsigned int* histBlk = (unsigned int*)alloc((size_t)EB * NP * 4);
  unsigned int* blkoff  = (unsigned int*)alloc((size_t)EB * NP * 4);
  unsigned int* partCnt = (unsigned int*)alloc((size_t)NP * 4);
  unsigned int* pe = (unsigned int*)alloc((size_t)NP * PCAP * 4);              // 6.4 MB packed edges
  int*   cnt = (int*)alloc((size_t)N_NODES * 4);
  float* dv  = (float*)alloc((size_t)(N_NODES + 1) * 4);                       // +1 sentinel
  unsigned short* esrc = (unsigned short*)alloc((size_t)N_NODES * CAP * 2);    // 6.4 MB u16 buckets
  unsigned short* hs    = (unsigned short*)alloc((size_t)NSLAB * PSTR * 2);    // slab-major h1 (+zero row)
  unsigned short* hbuf2 = (unsigned short*)alloc((size_t)(N_NODES + 1) * DIM * 2);  // +1 zero row
  unsigned short* aggh  = (unsigned short*)alloc((size_t)N_NODES * DIM * 2);   // agg1 hi plane
  unsigned short* aggl  = (unsigned short*)alloc((size_t)N_NODES * DIM * 2);   // agg1 lo plane
  float*          pf    = (float*)alloc((size_t)BATCH * DIM * 4);              // head plane fp32
  unsigned short* pth   = (unsigned short*)alloc((size_t)BATCH * DIM * 2);     // tail plane bf16 hi
  unsigned short* Qbf   = (unsigned short*)alloc((size_t)N_REL * DIM * DIM * 2);
  unsigned short* W1th  = (unsigned short*)alloc((size_t)DIM * DIM * 2);
  unsigned short* W1tl  = (unsigned short*)alloc((size_t)DIM * DIM * 2);
  unsigned short* W2th  = (unsigned short*)alloc((size_t)DIM * DIM * 2);
  unsigned short* W2tl  = (unsigned short*)alloc((size_t)DIM * DIM * 2);
  unsigned short* Mth   = (unsigned short*)alloc((size_t)DIM * DIM * 2);

  // 0: weight prep + sentinel zeroing
  k_prep<<<DIM * DIM / 256, 256, 0, stream>>>(W1, W2, M, W1th, W1tl, W2th, W2tl, Mth,
                                              hs, hbuf2, dv);
  // 1: per-block LDS histograms || decoder TQ
  k_histTQ<<<EB + G_TQ, 256, 0, stream>>>(dst, histBlk, Rel, Mth, Qbf);
  // 2: per-bin cross-block scan -> absolute offsets
  k_scanB<<<NP, 256, 0, stream>>>(histBlk, blkoff, partCnt);
  // 3: scatter packed edges to partitions (LDS slotting) || gemm1 (slab-major out)
  k_scatG<<<EB + G_GEMM, 256, 0, stream>>>(src, dst, blkoff, pe, init_emb, W1th, W1tl, hs);
  // 4: per-partition bucket fill (u16, pad-to-8) -> esrc + cnt + dinv
  k_build<<<NP, 256, 0, stream>>>(pe, partCnt, esrc, cnt, dv);
  // 5: agg1 by dim-slab over slab-major planes (L2-resident) -> hi/lo planes
  k_agg_slab<<<SLAB_GRID, 256, 0, stream>>>(hs, cnt, dv, esrc, b1, aggh, aggl);
  // 6: gemm2 from planes
  k_gemm_hl<<<(N_NODES + 127) / 128, 256, 0, stream>>>(aggh, aggl, W2th, W2tl, hbuf2, N_NODES);
  // 7: agg2 only at batch positions -> compact planes (head fp32, tail bf16)
  k_agg_batch<<<(2 * BATCH + 7) / 8, 256, 0, stream>>>(hbuf2, cnt, dv, esrc, b2, head, tail, pf, pth);
  // 8: predict (coalesced reads from compact planes)
  k_predict_mfma<<<dim3(BATCH / 128, N_REL), 256, 0, stream>>>(pf, pth, Qbf, out);
}

// Round 8
// 225.956 us; speedup vs baseline: 1.0691x; 1.0280x over previous
//
#include <hip/hip_runtime.h>

#define N_NODES 50000
#define N_EDGES 800000
#define DIM 128
#define N_REL 86
#define BATCH 2048
#define CAP 64               // per-node bucket capacity; max deg ~45 for Poisson(16)
#define ZROW N_NODES         // sentinel row: zeroed embedding row, dv[ZROW]=0 (fits u16)

#define NP 196               // partitions by dst>>8 (256 nodes each; ceil(50000/256))
#define EB 196               // edge blocks for build (4096 edges each)
#define PCAP 8192            // partition edge capacity (mean 4096, sigma 64)

#define NSLAB 4              // 32-dim slabs; slab-major planes: 3.2 MB each, L2-resident
#define PSTR ((size_t)(N_NODES + 1) * 32)                       // ushorts per slab plane
#define NODES_PER_BLK 32     // 256 threads / 8 lanes per node
#define NBLK ((N_NODES + NODES_PER_BLK - 1) / NODES_PER_BLK)    // 1563

using bf16x8 = __attribute__((ext_vector_type(8))) short;
using f32x4  = __attribute__((ext_vector_type(4))) float;

// float -> bf16 round-to-nearest-even (finite inputs)
static __device__ __forceinline__ unsigned short f2bf(float f) {
  union { float f; unsigned int i; } v; v.f = f;
  unsigned int x = v.i;
  unsigned int r = x + 0x7FFFu + ((x >> 16) & 1u);
  return (unsigned short)(r >> 16);
}
static __device__ __forceinline__ float bf2f(unsigned short u) {
  union { unsigned int i; float f; } v;
  v.i = ((unsigned int)u) << 16;
  return v.f;
}

#define G_TQ    172           // 86 relations x 2 d-blocks
#define G_GEMM  391           // ceil(50000/128)
#define TPAD 136              // 128+8 bf16: 272 B row stride -> 2-way bank alias (free)
#define QPAD 136

// ---------------- kernel 0: weight prep + sentinel-row zeroing + pcnt zero ----------------

__global__ __launch_bounds__(256) void k_prep(const float* __restrict__ W1, const float* __restrict__ W2,
                                              const float* __restrict__ M,
                                              unsigned short* __restrict__ W1th, unsigned short* __restrict__ W1tl,
                                              unsigned short* __restrict__ W2th, unsigned short* __restrict__ W2tl,
                                              unsigned short* __restrict__ Mth,
                                              unsigned short* __restrict__ hs,
                                              unsigned short* __restrict__ hbuf2,
                                              float* __restrict__ dv,
                                              unsigned int* __restrict__ pcnt) {
  int g = blockIdx.x * 256 + threadIdx.x;          // 16384 threads = DIM*DIM
  if (g < NP) pcnt[g] = 0u;                        // partition atomic counters
  // zero sentinel rows (gather pads resolve to ZROW; must be 0.0 not garbage/NaN)
  if (g < 32) {                                    // 4 slab planes x 8 ushort4
    ushort4 z = {0, 0, 0, 0};
    ((ushort4*)(hs + (size_t)(g >> 3) * PSTR))[(size_t)ZROW * 8 + (g & 7)] = z;
  }
  if (g >= 32 && g < 64) {                         // hbuf2 row (32 ushort4)
    ushort4 z = {0, 0, 0, 0};
    ((ushort4*)hbuf2)[(size_t)ZROW * 32 + (g - 32)] = z;
  }
  if (g == 64) dv[ZROW] = 0.f;
  int k = g >> 7, n = g & 127;
  int t = n * DIM + k;
  float w1 = W1[g];
  unsigned short h1 = f2bf(w1);
  W1th[t] = h1;
  W1tl[t] = f2bf(w1 - bf2f(h1));
  float w2 = W2[g];
  unsigned short h2 = f2bf(w2);
  W2th[t] = h2;
  W2tl[t] = f2bf(w2 - bf2f(h2));
  Mth[t] = f2bf(M[g]);
}

// ---------------- mega1: single-pass edge build (LDS hist -> atomic reserve -> scatter)
//                         ||  decoder TQ  ||  gemm1 (slab-major out) ----------------
// pe entry: (dst & 255) << 17 | src     (src < 50000 < 2^17)

__global__ __launch_bounds__(256) void k_mega1(const int* __restrict__ src, const int* __restrict__ dst,
                                               unsigned int* __restrict__ pcnt,
                                               unsigned int* __restrict__ pe,
                                               const float* __restrict__ Rel,
                                               const unsigned short* __restrict__ Mth,
                                               unsigned short* __restrict__ Qbf,
                                               const float* __restrict__ x,
                                               const unsigned short* __restrict__ W1th,
                                               const unsigned short* __restrict__ W1tl,
                                               unsigned short* __restrict__ hs) {
  __shared__ __align__(16) unsigned char smem[64 * TPAD * 2];   // max(hist 784B, Ts 17408B)
  int bid = blockIdx.x;
  union U { uint4 u; bf16x8 h; };

  if (bid < EB) {
    // ---- pass 1: LDS histogram of dst>>8 ----
    unsigned int* hist = (unsigned int*)smem;
    int t = threadIdx.x;
    if (t < NP) hist[t] = 0u;
    __syncthreads();
    #pragma unroll
    for (int j = 0; j < 4; ++j) {
      int i0 = bid * 4096 + j * 1024 + t * 4;
      if (i0 < N_EDGES) {
        int4 d4 = *(const int4*)(dst + i0);
        atomicAdd(&hist[d4.x >> 8], 1u);
        atomicAdd(&hist[d4.y >> 8], 1u);
        atomicAdd(&hist[d4.z >> 8], 1u);
        atomicAdd(&hist[d4.w >> 8], 1u);
      }
    }
    __syncthreads();
    // ---- reserve global ranges: one atomic per (block, bin) ----
    if (t < NP) {
      unsigned int c = hist[t];
      unsigned int base = c ? atomicAdd(&pcnt[t], c) : 0u;
      hist[t] = (unsigned int)t * PCAP + base;     // becomes this block's write cursor
    }
    __syncthreads();
    // ---- pass 2: scatter via LDS cursor ----
    #pragma unroll
    for (int j = 0; j < 4; ++j) {
      int i0 = bid * 4096 + j * 1024 + t * 4;
      if (i0 < N_EDGES) {
        int4 s4 = *(const int4*)(src + i0);
        int4 d4 = *(const int4*)(dst + i0);
        int b0 = d4.x >> 8, b1 = d4.y >> 8, b2 = d4.z >> 8, b3 = d4.w >> 8;
        unsigned int p0 = atomicAdd(&hist[b0], 1u);
        unsigned int p1 = atomicAdd(&hist[b1], 1u);
        unsigned int p2 = atomicAdd(&hist[b2], 1u);
        unsigned int p3 = atomicAdd(&hist[b3], 1u);
        if (p0 < (unsigned int)(b0 + 1) * PCAP) pe[p0] = ((unsigned)(d4.x & 255) << 17) | (unsigned)s4.x;
        if (p1 < (unsigned int)(b1 + 1) * PCAP) pe[p1] = ((unsigned)(d4.y & 255) << 17) | (unsigned)s4.y;
        if (p2 < (unsigned int)(b2 + 1) * PCAP) pe[p2] = ((unsigned)(d4.z & 255) << 17) | (unsigned)s4.z;
        if (p3 < (unsigned int)(b3 + 1) * PCAP) pe[p3] = ((unsigned)(d4.w & 255) << 17) | (unsigned)s4.w;
      }
    }
    return;
  }

  int wave = threadIdx.x >> 6, lane = threadIdx.x & 63;
  int l15 = lane & 15, quad = lane >> 4;

  if (bid < EB + G_TQ) {
    // ---- decoder precompute: T_r = Rel_r @ M (LDS), Q_r = T_r @ Rel_r^T ----
    unsigned short* Ts = (unsigned short*)smem;
    int tb = bid - EB;                       // [0, 172)
    int r = tb >> 1, dblk = tb & 1;
    const float* Rr = Rel + (size_t)r * DIM * DIM;
    unsigned short* Qr = Qbf + (size_t)r * DIM * DIM;
    int dw = dblk * 64 + wave * 16;
    f32x4 acc[8];
    #pragma unroll
    for (int nt = 0; nt < 8; ++nt) acc[nt] = f32x4{0.f, 0.f, 0.f, 0.f};
    #pragma unroll
    for (int ks = 0; ks < 4; ++ks) {
      int k0 = ks * 32 + quad * 8;
      const float* ap = Rr + (size_t)(dw + l15) * DIM + k0;
      float av[8];
      *(float4*)(av)     = *(const float4*)(ap);
      *(float4*)(av + 4) = *(const float4*)(ap + 4);
      bf16x8 a;
      #pragma unroll
      for (int j = 0; j < 8; ++j) a[j] = (short)f2bf(av[j]);
      #pragma unroll
      for (int nt = 0; nt < 8; ++nt) {
        U b; b.u = *(const uint4*)(Mth + (nt * 16 + l15) * DIM + k0);
        acc[nt] = __builtin_amdgcn_mfma_f32_16x16x32_bf16(a, b.h, acc[nt], 0, 0, 0);
      }
    }
    #pragma unroll
    for (int nt = 0; nt < 8; ++nt)
      #pragma unroll
      for (int reg = 0; reg < 4; ++reg)
        Ts[(wave * 16 + quad * 4 + reg) * TPAD + nt * 16 + l15] = f2bf(acc[nt][reg]);
    __syncthreads();
    f32x4 qacc[8];
    #pragma unroll
    for (int nt = 0; nt < 8; ++nt) qacc[nt] = f32x4{0.f, 0.f, 0.f, 0.f};
    #pragma unroll
    for (int ks = 0; ks < 4; ++ks) {
      int k0 = ks * 32 + quad * 8;
      U a; a.u = *(const uint4*)(Ts + (wave * 16 + l15) * TPAD + k0);
      #pragma unroll
      for (int nt = 0; nt < 8; ++nt) {
        const float* bp = Rr + (size_t)(nt * 16 + l15) * DIM + k0;
        float bv[8];
        *(float4*)(bv)     = *(const float4*)(bp);
        *(float4*)(bv + 4) = *(const float4*)(bp + 4);
        bf16x8 b;
        #pragma unroll
        for (int j = 0; j < 8; ++j) b[j] = (short)f2bf(bv[j]);
        qacc[nt] = __builtin_amdgcn_mfma_f32_16x16x32_bf16(a.h, b, qacc[nt], 0, 0, 0);
      }
    }
    #pragma unroll
    for (int nt = 0; nt < 8; ++nt)
      #pragma unroll
      for (int reg = 0; reg < 4; ++reg)
        Qr[(size_t)(dw + quad * 4 + reg) * DIM + nt * 16 + l15] = f2bf(qacc[nt][reg]);
    return;
  }

  // ---- node GEMM layer 1: hs = slab-major(x @ W1) (hi/lo 3-term, bf16 out) ----
  int r0 = (bid - EB - G_TQ) * 128 + wave * 32;
  f32x4 acc[2][8];
  #pragma unroll
  for (int mt = 0; mt < 2; ++mt)
    #pragma unroll
    for (int nt = 0; nt < 8; ++nt) acc[mt][nt] = f32x4{0.f, 0.f, 0.f, 0.f};
  #pragma unroll
  for (int ks = 0; ks < 4; ++ks) {
    int k0 = ks * 32 + quad * 8;
    bf16x8 ah[2], al[2];
    #pragma unroll
    for (int mt = 0; mt < 2; ++mt) {
      int row = r0 + mt * 16 + l15;
      row = (row < N_NODES) ? row : (N_NODES - 1);
      const float* xp = x + (size_t)row * DIM + k0;
      float xv[8];
      *(float4*)(xv)     = *(const float4*)(xp);
      *(float4*)(xv + 4) = *(const float4*)(xp + 4);
      #pragma unroll
      for (int j = 0; j < 8; ++j) {
        unsigned short h = f2bf(xv[j]);
        ah[mt][j] = (short)h;
        al[mt][j] = (short)f2bf(xv[j] - bf2f(h));
      }
    }
    #pragma unroll
    for (int nt = 0; nt < 8; ++nt) {
      U bh, bl;
      bh.u = *(const uint4*)(W1th + (nt * 16 + l15) * DIM + k0);
      bl.u = *(const uint4*)(W1tl + (nt * 16 + l15) * DIM + k0);
      #pragma unroll
      for (int mt = 0; mt < 2; ++mt) {
        acc[mt][nt] = __builtin_amdgcn_mfma_f32_16x16x32_bf16(ah[mt], bh.h, acc[mt][nt], 0, 0, 0);
        acc[mt][nt] = __builtin_amdgcn_mfma_f32_16x16x32_bf16(al[mt], bh.h, acc[mt][nt], 0, 0, 0);
        acc[mt][nt] = __builtin_amdgcn_mfma_f32_16x16x32_bf16(ah[mt], bl.h, acc[mt][nt], 0, 0, 0);
      }
    }
  }
  #pragma unroll
  for (int mt = 0; mt < 2; ++mt)
    #pragma unroll
    for (int reg = 0; reg < 4; ++reg) {
      int row = r0 + mt * 16 + quad * 4 + reg;
      if (row < N_NODES) {
        #pragma unroll
        for (int nt = 0; nt < 8; ++nt)
          hs[(size_t)(nt >> 1) * PSTR + (size_t)row * 32 + (nt & 1) * 16 + l15] = f2bf(acc[mt][nt][reg]);
      }
    }
}

// ---------------- build: per-partition bucket fill (u16) + pad-to-8 + cnt + dinv ----------------

__global__ __launch_bounds__(256) void k_build(const unsigned int* __restrict__ pe,
                                               const unsigned int* __restrict__ partCnt,
                                               unsigned short* __restrict__ esrc, int* __restrict__ cnt,
                                               float* __restrict__ dv) {
  __shared__ unsigned int c256[256];
  int p = blockIdx.x, t = threadIdx.x;
  c256[t] = 0u;
  __syncthreads();
  int m = min((int)partCnt[p], PCAP);
  for (int i = t; i < m; i += 256) {
    unsigned int e = pe[(size_t)p * PCAP + i];
    unsigned int local = e >> 17;
    unsigned int s = e & 0x1FFFFu;
    unsigned int slot = atomicAdd(&c256[local], 1u);
    int node = p * 256 + (int)local;
    if (slot < CAP) esrc[(size_t)node * CAP + slot] = (unsigned short)s;
  }
  __syncthreads();
  int node = p * 256 + t;
  if (node < N_NODES) {
    int c = (int)c256[t];
    cnt[node] = c;
    dv[node] = rsqrtf((float)(c + 1));
    int padded = min((c + 7) & ~7, CAP);          // pad bucket to multiple of 8
    for (int s = c; s < padded; ++s) esrc[(size_t)node * CAP + s] = (unsigned short)ZROW;
  }
}

// ---------------- agg1 by dim-slab, SLAB-SEQUENTIAL ordering ----------------
// slab = bid / NBLK: ~1300 resident blocks ~= one slab's worth, so at any instant
// every XCD's L2 caches the SAME 3.2 MB plane (replicated) -> true residency.
// 8 lanes per node: lane loads ushort4 (8B); group covers the full 64 B row-slab.

__global__ __launch_bounds__(256) void k_agg_slab(const unsigned short* __restrict__ hs,
                                                  const int* __restrict__ cnt,
                                                  const float* __restrict__ dv,
                                                  const unsigned short* __restrict__ esrc,
                                                  const float* __restrict__ bias,
                                                  unsigned short* __restrict__ outh,
                                                  unsigned short* __restrict__ outl) {
  int bid = blockIdx.x;
  int slab = bid / NBLK;
  int nb = bid % NBLK;
  int grp = threadIdx.x >> 3, lane8 = threadIdx.x & 7;
  int node = nb * NODES_PER_BLK + grp;
  if (node >= N_NODES) return;

  const ushort4* h4 = (const ushort4*)(hs + (size_t)slab * PSTR);   // 8 x ushort4 per row-slab
  int deg = cnt[node];
  int end = min((deg + 7) & ~7, CAP);             // padded multiple of 8
  float di = dv[node];
  ushort4 hv = h4[(size_t)node * 8 + lane8];
  float ax = di * bf2f(hv.x), ay = di * bf2f(hv.y), az = di * bf2f(hv.z), aw = di * bf2f(hv.w);
  float bx = 0.f, by = 0.f, bz = 0.f, bw = 0.f;
  const unsigned short* eb = esrc + (size_t)node * CAP;
  for (int e = 0; e < end; e += 8) {
    ushort4 iA = *(const ushort4*)(eb + e);       // 8 u16 indices (16 B, aligned)
    ushort4 iB = *(const ushort4*)(eb + e + 4);
    ushort4 v0 = h4[(size_t)iA.x * 8 + lane8];
    ushort4 v1 = h4[(size_t)iA.y * 8 + lane8];
    ushort4 v2 = h4[(size_t)iA.z * 8 + lane8];
    ushort4 v3 = h4[(size_t)iA.w * 8 + lane8];
    ushort4 v4 = h4[(size_t)iB.x * 8 + lane8];
    ushort4 v5 = h4[(size_t)iB.y * 8 + lane8];
    ushort4 v6 = h4[(size_t)iB.z * 8 + lane8];
    ushort4 v7 = h4[(size_t)iB.w * 8 + lane8];
    float d0 = dv[iA.x], d1 = dv[iA.y], d2 = dv[iA.z], d3 = dv[iA.w];
    float d4 = dv[iB.x], d5 = dv[iB.y], d6 = dv[iB.z], d7 = dv[iB.w];
    ax = fmaf(d0, bf2f(v0.x), ax); ay = fmaf(d0, bf2f(v0.y), ay); az = fmaf(d0, bf2f(v0.z), az); aw = fmaf(d0, bf2f(v0.w), aw);
    bx = fmaf(d1, bf2f(v1.x), bx); by = fmaf(d1, bf2f(v1.y), by); bz = fmaf(d1, bf2f(v1.z), bz); bw = fmaf(d1, bf2f(v1.w), bw);
    ax = fmaf(d2, bf2f(v2.x), ax); ay = fmaf(d2, bf2f(v2.y), ay); az = fmaf(d2, bf2f(v2.z), az); aw = fmaf(d2, bf2f(v2.w), aw);
    bx = fmaf(d3, bf2f(v3.x), bx); by = fmaf(d3, bf2f(v3.y), by); bz = fmaf(d3, bf2f(v3.z), bz); bw = fmaf(d3, bf2f(v3.w), bw);
    ax = fmaf(d4, bf2f(v4.x), ax); ay = fmaf(d4, bf2f(v4.y), ay); az = fmaf(d4, bf2f(v4.z), az); aw = fmaf(d4, bf2f(v4.w), aw);
    bx = fmaf(d5, bf2f(v5.x), bx); by = fmaf(d5, bf2f(v5.y), by); bz = fmaf(d5, bf2f(v5.z), bz); bw = fmaf(d5, bf2f(v5.w), bw);
    ax = fmaf(d6, bf2f(v6.x), ax); ay = fmaf(d6, bf2f(v6.y), ay); az = fmaf(d6, bf2f(v6.z), az); aw = fmaf(d6, bf2f(v6.w), aw);
    bx = fmaf(d7, bf2f(v7.x), bx); by = fmaf(d7, bf2f(v7.y), by); bz = fmaf(d7, bf2f(v7.z), bz); bw = fmaf(d7, bf2f(v7.w), bw);
  }
  ax += bx; ay += by; az += bz; aw += bw;
  int base4 = slab * 8 + lane8;
  float4 bb = ((const float4*)bias)[base4];
  float vx = fmaf(di, ax, bb.x), vy = fmaf(di, ay, bb.y);
  float vz = fmaf(di, az, bb.z), vw = fmaf(di, aw, bb.w);
  ushort4 hi4, lo4;
  hi4.x = f2bf(vx); lo4.x = f2bf(vx - bf2f(hi4.x));
  hi4.y = f2bf(vy); lo4.y = f2bf(vy - bf2f(hi4.y));
  hi4.z = f2bf(vz); lo4.z = f2bf(vz - bf2f(hi4.z));
  hi4.w = f2bf(vw); lo4.w = f2bf(vw - bf2f(hi4.w));
  ((ushort4*)outh)[(size_t)node * 32 + base4] = hi4;
  ((ushort4*)outl)[(size_t)node * 32 + base4] = lo4;
}

// ---------------- gemm2: A from hi/lo planes, 3-term, bf16 out (row-major) ----------------

__global__ __launch_bounds__(256) void k_gemm_hl(const unsigned short* __restrict__ xh,
                                                 const unsigned short* __restrict__ xl,
                                                 const unsigned short* __restrict__ Wth,
                                                 const unsigned short* __restrict__ Wtl,
                                                 unsigned short* __restrict__ out, int nrows) {
  int wave = threadIdx.x >> 6, lane = threadIdx.x & 63;
  int l15 = lane & 15, quad = lane >> 4;
  int r0 = blockIdx.x * 128 + wave * 32;
  f32x4 acc[2][8];
  #pragma unroll
  for (int mt = 0; mt < 2; ++mt)
    #pragma unroll
    for (int nt = 0; nt < 8; ++nt) acc[mt][nt] = f32x4{0.f, 0.f, 0.f, 0.f};
  union U { uint4 u; bf16x8 h; };
  #pragma unroll
  for (int ks = 0; ks < 4; ++ks) {
    int k0 = ks * 32 + quad * 8;
    U ah[2], al[2];
    #pragma unroll
    for (int mt = 0; mt < 2; ++mt) {
      int row = r0 + mt * 16 + l15;
      row = (row < nrows) ? row : (nrows - 1);
      ah[mt].u = *(const uint4*)(xh + (size_t)row * DIM + k0);
      al[mt].u = *(const uint4*)(xl + (size_t)row * DIM + k0);
    }
    #pragma unroll
    for (int nt = 0; nt < 8; ++nt) {
      U bh, bl;
      bh.u = *(const uint4*)(Wth + (nt * 16 + l15) * DIM + k0);
      bl.u = *(const uint4*)(Wtl + (nt * 16 + l15) * DIM + k0);
      #pragma unroll
      for (int mt = 0; mt < 2; ++mt) {
        acc[mt][nt] = __builtin_amdgcn_mfma_f32_16x16x32_bf16(ah[mt].h, bh.h, acc[mt][nt], 0, 0, 0);
        acc[mt][nt] = __builtin_amdgcn_mfma_f32_16x16x32_bf16(al[mt].h, bh.h, acc[mt][nt], 0, 0, 0);
        acc[mt][nt] = __builtin_amdgcn_mfma_f32_16x16x32_bf16(ah[mt].h, bl.h, acc[mt][nt], 0, 0, 0);
      }
    }
  }
  #pragma unroll
  for (int mt = 0; mt < 2; ++mt)
    #pragma unroll
    for (int reg = 0; reg < 4; ++reg) {
      int row = r0 + mt * 16 + quad * 4 + reg;
      if (row < nrows) {
        #pragma unroll
        for (int nt = 0; nt < 8; ++nt)
          out[(size_t)row * DIM + nt * 16 + l15] = f2bf(acc[mt][nt][reg]);
      }
    }
}

// ---------------- full-row aggregation core (used by agg_batch only; hbuf2 row-major) ----------------

static __device__ __forceinline__ float4 agg_compute(const unsigned short* __restrict__ h,
                                                     const int* __restrict__ cnt,
                                                     const float* __restrict__ dv,
                                                     const unsigned short* __restrict__ esrc,
                                                     const float* __restrict__ bias,
                                                     int node, int lane) {
  const ushort4* h4 = (const ushort4*)h;
  int deg = cnt[node];
  int end = min((deg + 7) & ~7, CAP);              // padded length, multiple of 8
  float di = dv[node];
  ushort4 hv = h4[(size_t)node * 32 + lane];
  float ax = di * bf2f(hv.x), ay = di * bf2f(hv.y), az = di * bf2f(hv.z), aw = di * bf2f(hv.w);
  float bx = 0.f, by = 0.f, bz = 0.f, bw = 0.f;
  const unsigned short* eb = esrc + (size_t)node * CAP;
  for (int e = 0; e < end; e += 8) {
    ushort4 iA = *(const ushort4*)(eb + e);
    ushort4 iB = *(const ushort4*)(eb + e + 4);
    ushort4 v0 = h4[(size_t)iA.x * 32 + lane];
    ushort4 v1 = h4[(size_t)iA.y * 32 + lane];
    ushort4 v2 = h4[(size_t)iA.z * 32 + lane];
    ushort4 v3 = h4[(size_t)iA.w * 32 + lane];
    ushort4 v4 = h4[(size_t)iB.x * 32 + lane];
    ushort4 v5 = h4[(size_t)iB.y * 32 + lane];
    ushort4 v6 = h4[(size_t)iB.z * 32 + lane];
    ushort4 v7 = h4[(size_t)iB.w * 32 + lane];
    float d0 = dv[iA.x], d1 = dv[iA.y], d2 = dv[iA.z], d3 = dv[iA.w];
    float d4 = dv[iB.x], d5 = dv[iB.y], d6 = dv[iB.z], d7 = dv[iB.w];
    ax = fmaf(d0, bf2f(v0.x), ax); ay = fmaf(d0, bf2f(v0.y), ay); az = fmaf(d0, bf2f(v0.z), az); aw = fmaf(d0, bf2f(v0.w), aw);
    bx = fmaf(d1, bf2f(v1.x), bx); by = fmaf(d1, bf2f(v1.y), by); bz = fmaf(d1, bf2f(v1.z), bz); bw = fmaf(d1, bf2f(v1.w), bw);
    ax = fmaf(d2, bf2f(v2.x), ax); ay = fmaf(d2, bf2f(v2.y), ay); az = fmaf(d2, bf2f(v2.z), az); aw = fmaf(d2, bf2f(v2.w), aw);
    bx = fmaf(d3, bf2f(v3.x), bx); by = fmaf(d3, bf2f(v3.y), by); bz = fmaf(d3, bf2f(v3.z), bz); bw = fmaf(d3, bf2f(v3.w), bw);
    ax = fmaf(d4, bf2f(v4.x), ax); ay = fmaf(d4, bf2f(v4.y), ay); az = fmaf(d4, bf2f(v4.z), az); aw = fmaf(d4, bf2f(v4.w), aw);
    bx = fmaf(d5, bf2f(v5.x), bx); by = fmaf(d5, bf2f(v5.y), by); bz = fmaf(d5, bf2f(v5.z), bz); bw = fmaf(d5, bf2f(v5.w), bw);
    ax = fmaf(d6, bf2f(v6.x), ax); ay = fmaf(d6, bf2f(v6.y), ay); az = fmaf(d6, bf2f(v6.z), az); aw = fmaf(d6, bf2f(v6.w), aw);
    bx = fmaf(d7, bf2f(v7.x), bx); by = fmaf(d7, bf2f(v7.y), by); bz = fmaf(d7, bf2f(v7.z), bz); bw = fmaf(d7, bf2f(v7.w), bw);
  }
  ax += bx; ay += by; az += bz; aw += bw;
  float4 bb = ((const float4*)bias)[lane];
  float4 v;
  v.x = fmaf(di, ax, bb.x); v.y = fmaf(di, ay, bb.y);
  v.z = fmaf(di, az, bb.z); v.w = fmaf(di, aw, bb.w);
  return v;
}

// ---------------- agg2 at batch positions only ----------------
// head rows -> fp32 plane pf[BATCH][128]; tail rows -> bf16 hi plane pth[BATCH][128]

__global__ __launch_bounds__(256) void k_agg_batch(const unsigned short* __restrict__ h,
                                                   const int* __restrict__ cnt,
                                                   const float* __restrict__ dv,
                                                   const unsigned short* __restrict__ esrc,
                                                   const float* __restrict__ bias,
                                                   const int* __restrict__ head,
                                                   const int* __restrict__ tail,
                                                   float* __restrict__ pf,
                                                   unsigned short* __restrict__ pth) {
  int pos = blockIdx.x * 8 + (threadIdx.x >> 5);
  if (pos >= 2 * BATCH) return;
  int lane = threadIdx.x & 31;
  int node = (pos < BATCH) ? head[pos] : tail[pos - BATCH];
  float4 v = agg_compute(h, cnt, dv, esrc, bias, node, lane);
  if (pos < BATCH) {
    ((float4*)pf)[(size_t)pos * 32 + lane] = v;
  } else {
    ushort4 hi4 = { f2bf(v.x), f2bf(v.y), f2bf(v.z), f2bf(v.w) };
    ((ushort4*)pth)[(size_t)(pos - BATCH) * 32 + lane] = hi4;
  }
}

// ---------------- predict via MFMA: tail (bf16) @ Q_r, dot with head (fp32) ----------------

__global__ __launch_bounds__(256) void k_predict_mfma(const float* __restrict__ pf,
                                                      const unsigned short* __restrict__ pth,
                                                      const unsigned short* __restrict__ Qbf,
                                                      float* __restrict__ out) {
  __shared__ __align__(16) unsigned short Qs[DIM * QPAD];
  int r = blockIdx.y;
  const unsigned short* Qr = Qbf + (size_t)r * DIM * DIM;
  for (int i = threadIdx.x; i < DIM * DIM / 8; i += 256) {
    int d = i >> 4, c = (i & 15) * 8;
    uint4 v = ((const uint4*)Qr)[i];
    *(uint4*)(&Qs[d * QPAD + c]) = v;
  }
  __syncthreads();
  int wave = threadIdx.x >> 6, lane = threadIdx.x & 63;
  int l15 = lane & 15, quad = lane >> 4;
  int bbase = blockIdx.x * 128 + wave * 32;
  int t0 = bbase + l15;                    // tail plane rows (coalesced, no gather)
  int t1 = bbase + 16 + l15;

  f32x4 acc[2][8];
  #pragma unroll
  for (int m = 0; m < 2; ++m)
    #pragma unroll
    for (int n = 0; n < 8; ++n) acc[m][n] = f32x4{0.f, 0.f, 0.f, 0.f};

  union U { uint4 u; bf16x8 h; };
  #pragma unroll
  for (int ks = 0; ks < 4; ++ks) {
    int eoff = ks * 32 + quad * 8;
    U a0, a1;
    a0.u = *(const uint4*)(pth + (size_t)t0 * DIM + eoff);
    a1.u = *(const uint4*)(pth + (size_t)t1 * DIM + eoff);
    #pragma unroll
    for (int nt = 0; nt < 8; ++nt) {
      U b; b.u = *(const uint4*)(&Qs[(nt * 16 + l15) * QPAD + eoff]);
      acc[0][nt] = __builtin_amdgcn_mfma_f32_16x16x32_bf16(a0.h, b.h, acc[0][nt], 0, 0, 0);
      acc[1][nt] = __builtin_amdgcn_mfma_f32_16x16x32_bf16(a1.h, b.h, acc[1][nt], 0, 0, 0);
    }
  }

  #pragma unroll
  for (int m = 0; m < 2; ++m) {
    #pragma unroll
    for (int reg = 0; reg < 4; ++reg) {
      int bl = bbase + m * 16 + quad * 4 + reg;             // batch index == head plane row
      float s = 0.f;
      #pragma unroll
      for (int nt = 0; nt < 8; ++nt)
        s += pf[(size_t)bl * DIM + nt * 16 + l15] * acc[m][nt][reg];   // head = fp32 plane
      #pragma unroll
      for (int off = 1; off < 16; off <<= 1) s += __shfl_xor(s, off, 64);
      if (l15 == 0) out[(size_t)bl * N_REL + r] = s;
    }
  }
}

// ---------------- launch ----------------

extern "C" void kernel_launch(void* const* d_in, const int* in_sizes, int n_in,
                              void* d_out, int out_size, void* d_ws, size_t ws_size,
                              hipStream_t stream) {
  (void)in_sizes; (void)n_in; (void)out_size; (void)ws_size;
  const float* init_emb = (const float*)d_in[0];
  const float* W1  = (const float*)d_in[1];
  const float* b1  = (const float*)d_in[2];
  const float* W2  = (const float*)d_in[3];
  const float* b2  = (const float*)d_in[4];
  const float* Rel = (const float*)d_in[5];
  const float* M   = (const float*)d_in[6];
  const int* head  = (const int*)d_in[7];
  const int* tail  = (const int*)d_in[8];
  const int* src   = (const int*)d_in[9];
  const int* dst   = src + N_EDGES;
  float* out = (float*)d_out;

  char* p = (char*)d_ws;
  auto alloc = [&](size_t bytes) { char* q = p; p += (bytes + 511) & ~(size_t)511; return q; };
  unsigned int* pcnt = (unsigned int*)alloc((size_t)NP * 4);                   // atomic partition counters
  unsigned int* pe = (unsigned int*)alloc((size_t)NP * PCAP * 4);              // 6.4 MB packed edges
  int*   cnt = (int*)alloc((size_t)N_NODES * 4);
  float* dv  = (float*)alloc((size_t)(N_NODES + 1) * 4);                       // +1 sentinel
  unsigned short* esrc = (unsigned short*)alloc((size_t)N_NODES * CAP * 2);    // 6.4 MB u16 buckets
  unsigned short* hs    = (unsigned short*)alloc((size_t)NSLAB * PSTR * 2);    // slab-major h1 (+zero row)
  unsigned short* hbuf2 = (unsigned short*)alloc((size_t)(N_NODES + 1) * DIM * 2);  // +1 zero row
  unsigned short* aggh  = (unsigned short*)alloc((size_t)N_NODES * DIM * 2);   // agg1 hi plane
  unsigned short* aggl  = (unsigned short*)alloc((size_t)N_NODES * DIM * 2);   // agg1 lo plane
  float*          pf    = (float*)alloc((size_t)BATCH * DIM * 4);              // head plane fp32
  unsigned short* pth   = (unsigned short*)alloc((size_t)BATCH * DIM * 2);     // tail plane bf16 hi
  unsigned short* Qbf   = (unsigned short*)alloc((size_t)N_REL * DIM * DIM * 2);
  unsigned short* W1th  = (unsigned short*)alloc((size_t)DIM * DIM * 2);
  unsigned short* W1tl  = (unsigned short*)alloc((size_t)DIM * DIM * 2);
  unsigned short* W2th  = (unsigned short*)alloc((size_t)DIM * DIM * 2);
  unsigned short* W2tl  = (unsigned short*)alloc((size_t)DIM * DIM * 2);
  unsigned short* Mth   = (unsigned short*)alloc((size_t)DIM * DIM * 2);

  // 0: weight prep + sentinel zeroing + pcnt zero
  k_prep<<<DIM * DIM / 256, 256, 0, stream>>>(W1, W2, M, W1th, W1tl, W2th, W2tl, Mth,
                                              hs, hbuf2, dv, pcnt);
  // 1: single-pass edge build (hist -> reserve -> scatter) || decoder TQ || gemm1
  k_mega1<<<EB + G_TQ + G_GEMM, 256, 0, stream>>>(src, dst, pcnt, pe, Rel, Mth, Qbf,
                                                  init_emb, W1th, W1tl, hs);
  // 2: per-partition bucket fill (u16, pad-to-8) -> esrc + cnt + dinv
  k_build<<<NP, 256, 0, stream>>>(pe, pcnt, esrc, cnt, dv);
  // 3: agg1 by dim-slab, slab-sequential (one plane L2-resident at a time) -> hi/lo planes
  k_agg_slab<<<NSLAB * NBLK, 256, 0, stream>>>(hs, cnt, dv, esrc, b1, aggh, aggl);
  // 4: gemm2 from planes
  k_gemm_hl<<<(N_NODES + 127) / 128, 256, 0, stream>>>(aggh, aggl, W2th, W2tl, hbuf2, N_NODES);
  // 5: agg2 only at batch positions -> compact planes (head fp32, tail bf16)
  k_agg_batch<<<(2 * BATCH + 7) / 8, 256, 0, stream>>>(hbuf2, cnt, dv, esrc, b2, head, tail, pf, pth);
  // 6: predict (coalesced reads from compact planes)
  k_predict_mfma<<<dim3(BATCH / 128, N_REL), 256, 0, stream>>>(pf, pth, Qbf, out);
}

// Round 9
// 216.657 us; speedup vs baseline: 1.1150x; 1.0429x over previous
//
#include <hip/hip_runtime.h>

#define N_NODES 50000
#define N_EDGES 800000
#define DIM 128
#define N_REL 86
#define BATCH 2048
#define CAP 64               // per-node bucket capacity; max deg ~45 for Poisson(16)
#define ZROW N_NODES         // sentinel row: zeroed embedding row, dv[ZROW]=0 (fits u16)

#define NP 196               // partitions by dst>>8 (256 nodes each; ceil(50000/256))
#define EB 196               // edge blocks for build (4096 edges each)
#define PCAP 8192            // partition edge capacity (mean 4096, sigma 64)

#define NSLAB 2              // 64-dim slabs; 16 lanes/node cover 128 B row-slab
#define PSTR ((size_t)(N_NODES + 1) * 64)                       // ushorts per slab plane
#define NODES_PER_BLK 16     // 256 threads / 16 lanes per node
#define NBLK (N_NODES / NODES_PER_BLK)                          // 3125 exact

using bf16x8 = __attribute__((ext_vector_type(8))) short;
using f32x4  = __attribute__((ext_vector_type(4))) float;

// float -> bf16 round-to-nearest-even (finite inputs)
static __device__ __forceinline__ unsigned short f2bf(float f) {
  union { float f; unsigned int i; } v; v.f = f;
  unsigned int x = v.i;
  unsigned int r = x + 0x7FFFu + ((x >> 16) & 1u);
  return (unsigned short)(r >> 16);
}
static __device__ __forceinline__ float bf2f(unsigned short u) {
  union { unsigned int i; float f; } v;
  v.i = ((unsigned int)u) << 16;
  return v.f;
}

#define G_TQ    172           // 86 relations x 2 d-blocks
#define G_GEMM  391           // ceil(50000/128)
#define TPAD 136              // 128+8 bf16: 272 B row stride -> 2-way bank alias (free)
#define QPAD 136

// ---------------- kernel 0: weight prep + sentinel-row zeroing + pcnt zero ----------------

__global__ __launch_bounds__(256) void k_prep(const float* __restrict__ W1, const float* __restrict__ W2,
                                              const float* __restrict__ M,
                                              unsigned short* __restrict__ W1th, unsigned short* __restrict__ W1tl,
                                              unsigned short* __restrict__ W2th, unsigned short* __restrict__ W2tl,
                                              unsigned short* __restrict__ Mth,
                                              unsigned short* __restrict__ hs,
                                              unsigned short* __restrict__ hbuf2,
                                              float* __restrict__ dv,
                                              unsigned int* __restrict__ pcnt) {
  int g = blockIdx.x * 256 + threadIdx.x;          // 16384 threads = DIM*DIM
  if (g < NP) pcnt[g] = 0u;                        // partition atomic counters
  // zero sentinel rows (gather pads resolve to ZROW; must be 0.0 not garbage/NaN)
  if (g < 32) {                                    // 2 slab planes x 16 ushort4
    ushort4 z = {0, 0, 0, 0};
    ((ushort4*)(hs + (size_t)(g >> 4) * PSTR))[(size_t)ZROW * 16 + (g & 15)] = z;
  }
  if (g >= 32 && g < 64) {                         // hbuf2 row (32 ushort4)
    ushort4 z = {0, 0, 0, 0};
    ((ushort4*)hbuf2)[(size_t)ZROW * 32 + (g - 32)] = z;
  }
  if (g == 64) dv[ZROW] = 0.f;
  int k = g >> 7, n = g & 127;
  int t = n * DIM + k;
  float w1 = W1[g];
  unsigned short h1 = f2bf(w1);
  W1th[t] = h1;
  W1tl[t] = f2bf(w1 - bf2f(h1));
  float w2 = W2[g];
  unsigned short h2 = f2bf(w2);
  W2th[t] = h2;
  W2tl[t] = f2bf(w2 - bf2f(h2));
  Mth[t] = f2bf(M[g]);
}

// ---------------- mega1: single-pass edge build (LDS hist -> atomic reserve -> scatter)
//                         ||  decoder TQ  ||  gemm1 (slab-major out) ----------------
// pe entry: (dst & 255) << 17 | src     (src < 50000 < 2^17)

__global__ __launch_bounds__(256) void k_mega1(const int* __restrict__ src, const int* __restrict__ dst,
                                               unsigned int* __restrict__ pcnt,
                                               unsigned int* __restrict__ pe,
                                               const float* __restrict__ Rel,
                                               const unsigned short* __restrict__ Mth,
                                               unsigned short* __restrict__ Qbf,
                                               const float* __restrict__ x,
                                               const unsigned short* __restrict__ W1th,
                                               const unsigned short* __restrict__ W1tl,
                                               unsigned short* __restrict__ hs) {
  __shared__ __align__(16) unsigned char smem[64 * TPAD * 2];   // max(hist 784B, Ts 17408B)
  int bid = blockIdx.x;
  union U { uint4 u; bf16x8 h; };

  if (bid < EB) {
    // ---- pass 1: LDS histogram of dst>>8 ----
    unsigned int* hist = (unsigned int*)smem;
    int t = threadIdx.x;
    if (t < NP) hist[t] = 0u;
    __syncthreads();
    #pragma unroll
    for (int j = 0; j < 4; ++j) {
      int i0 = bid * 4096 + j * 1024 + t * 4;
      if (i0 < N_EDGES) {
        int4 d4 = *(const int4*)(dst + i0);
        atomicAdd(&hist[d4.x >> 8], 1u);
        atomicAdd(&hist[d4.y >> 8], 1u);
        atomicAdd(&hist[d4.z >> 8], 1u);
        atomicAdd(&hist[d4.w >> 8], 1u);
      }
    }
    __syncthreads();
    // ---- reserve global ranges: one atomic per (block, bin) ----
    if (t < NP) {
      unsigned int c = hist[t];
      unsigned int base = c ? atomicAdd(&pcnt[t], c) : 0u;
      hist[t] = (unsigned int)t * PCAP + base;     // becomes this block's write cursor
    }
    __syncthreads();
    // ---- pass 2: scatter via LDS cursor ----
    #pragma unroll
    for (int j = 0; j < 4; ++j) {
      int i0 = bid * 4096 + j * 1024 + t * 4;
      if (i0 < N_EDGES) {
        int4 s4 = *(const int4*)(src + i0);
        int4 d4 = *(const int4*)(dst + i0);
        int b0 = d4.x >> 8, b1 = d4.y >> 8, b2 = d4.z >> 8, b3 = d4.w >> 8;
        unsigned int p0 = atomicAdd(&hist[b0], 1u);
        unsigned int p1 = atomicAdd(&hist[b1], 1u);
        unsigned int p2 = atomicAdd(&hist[b2], 1u);
        unsigned int p3 = atomicAdd(&hist[b3], 1u);
        if (p0 < (unsigned int)(b0 + 1) * PCAP) pe[p0] = ((unsigned)(d4.x & 255) << 17) | (unsigned)s4.x;
        if (p1 < (unsigned int)(b1 + 1) * PCAP) pe[p1] = ((unsigned)(d4.y & 255) << 17) | (unsigned)s4.y;
        if (p2 < (unsigned int)(b2 + 1) * PCAP) pe[p2] = ((unsigned)(d4.z & 255) << 17) | (unsigned)s4.z;
        if (p3 < (unsigned int)(b3 + 1) * PCAP) pe[p3] = ((unsigned)(d4.w & 255) << 17) | (unsigned)s4.w;
      }
    }
    return;
  }

  int wave = threadIdx.x >> 6, lane = threadIdx.x & 63;
  int l15 = lane & 15, quad = lane >> 4;

  if (bid < EB + G_TQ) {
    // ---- decoder precompute: T_r = Rel_r @ M (LDS), Q_r = T_r @ Rel_r^T ----
    unsigned short* Ts = (unsigned short*)smem;
    int tb = bid - EB;                       // [0, 172)
    int r = tb >> 1, dblk = tb & 1;
    const float* Rr = Rel + (size_t)r * DIM * DIM;
    unsigned short* Qr = Qbf + (size_t)r * DIM * DIM;
    int dw = dblk * 64 + wave * 16;
    f32x4 acc[8];
    #pragma unroll
    for (int nt = 0; nt < 8; ++nt) acc[nt] = f32x4{0.f, 0.f, 0.f, 0.f};
    #pragma unroll
    for (int ks = 0; ks < 4; ++ks) {
      int k0 = ks * 32 + quad * 8;
      const float* ap = Rr + (size_t)(dw + l15) * DIM + k0;
      float av[8];
      *(float4*)(av)     = *(const float4*)(ap);
      *(float4*)(av + 4) = *(const float4*)(ap + 4);
      bf16x8 a;
      #pragma unroll
      for (int j = 0; j < 8; ++j) a[j] = (short)f2bf(av[j]);
      #pragma unroll
      for (int nt = 0; nt < 8; ++nt) {
        U b; b.u = *(const uint4*)(Mth + (nt * 16 + l15) * DIM + k0);
        acc[nt] = __builtin_amdgcn_mfma_f32_16x16x32_bf16(a, b.h, acc[nt], 0, 0, 0);
      }
    }
    #pragma unroll
    for (int nt = 0; nt < 8; ++nt)
      #pragma unroll
      for (int reg = 0; reg < 4; ++reg)
        Ts[(wave * 16 + quad * 4 + reg) * TPAD + nt * 16 + l15] = f2bf(acc[nt][reg]);
    __syncthreads();
    f32x4 qacc[8];
    #pragma unroll
    for (int nt = 0; nt < 8; ++nt) qacc[nt] = f32x4{0.f, 0.f, 0.f, 0.f};
    #pragma unroll
    for (int ks = 0; ks < 4; ++ks) {
      int k0 = ks * 32 + quad * 8;
      U a; a.u = *(const uint4*)(Ts + (wave * 16 + l15) * TPAD + k0);
      #pragma unroll
      for (int nt = 0; nt < 8; ++nt) {
        const float* bp = Rr + (size_t)(nt * 16 + l15) * DIM + k0;
        float bv[8];
        *(float4*)(bv)     = *(const float4*)(bp);
        *(float4*)(bv + 4) = *(const float4*)(bp + 4);
        bf16x8 b;
        #pragma unroll
        for (int j = 0; j < 8; ++j) b[j] = (short)f2bf(bv[j]);
        qacc[nt] = __builtin_amdgcn_mfma_f32_16x16x32_bf16(a.h, b, qacc[nt], 0, 0, 0);
      }
    }
    #pragma unroll
    for (int nt = 0; nt < 8; ++nt)
      #pragma unroll
      for (int reg = 0; reg < 4; ++reg)
        Qr[(size_t)(dw + quad * 4 + reg) * DIM + nt * 16 + l15] = f2bf(qacc[nt][reg]);
    return;
  }

  // ---- node GEMM layer 1: hs = slab-major(x @ W1) (hi/lo 3-term, bf16 out) ----
  int r0 = (bid - EB - G_TQ) * 128 + wave * 32;
  f32x4 acc[2][8];
  #pragma unroll
  for (int mt = 0; mt < 2; ++mt)
    #pragma unroll
    for (int nt = 0; nt < 8; ++nt) acc[mt][nt] = f32x4{0.f, 0.f, 0.f, 0.f};
  #pragma unroll
  for (int ks = 0; ks < 4; ++ks) {
    int k0 = ks * 32 + quad * 8;
    bf16x8 ah[2], al[2];
    #pragma unroll
    for (int mt = 0; mt < 2; ++mt) {
      int row = r0 + mt * 16 + l15;
      row = (row < N_NODES) ? row : (N_NODES - 1);
      const float* xp = x + (size_t)row * DIM + k0;
      float xv[8];
      *(float4*)(xv)     = *(const float4*)(xp);
      *(float4*)(xv + 4) = *(const float4*)(xp + 4);
      #pragma unroll
      for (int j = 0; j < 8; ++j) {
        unsigned short h = f2bf(xv[j]);
        ah[mt][j] = (short)h;
        al[mt][j] = (short)f2bf(xv[j] - bf2f(h));
      }
    }
    #pragma unroll
    for (int nt = 0; nt < 8; ++nt) {
      U bh, bl;
      bh.u = *(const uint4*)(W1th + (nt * 16 + l15) * DIM + k0);
      bl.u = *(const uint4*)(W1tl + (nt * 16 + l15) * DIM + k0);
      #pragma unroll
      for (int mt = 0; mt < 2; ++mt) {
        acc[mt][nt] = __builtin_amdgcn_mfma_f32_16x16x32_bf16(ah[mt], bh.h, acc[mt][nt], 0, 0, 0);
        acc[mt][nt] = __builtin_amdgcn_mfma_f32_16x16x32_bf16(al[mt], bh.h, acc[mt][nt], 0, 0, 0);
        acc[mt][nt] = __builtin_amdgcn_mfma_f32_16x16x32_bf16(ah[mt], bl.h, acc[mt][nt], 0, 0, 0);
      }
    }
  }
  #pragma unroll
  for (int mt = 0; mt < 2; ++mt)
    #pragma unroll
    for (int reg = 0; reg < 4; ++reg) {
      int row = r0 + mt * 16 + quad * 4 + reg;
      if (row < N_NODES) {
        #pragma unroll
        for (int nt = 0; nt < 8; ++nt)
          hs[(size_t)(nt >> 2) * PSTR + (size_t)row * 64 + (nt & 3) * 16 + l15] = f2bf(acc[mt][nt][reg]);
      }
    }
}

// ---------------- build: per-partition bucket fill (u16) + pad-to-8 + cnt + dinv ----------------

__global__ __launch_bounds__(256) void k_build(const unsigned int* __restrict__ pe,
                                               const unsigned int* __restrict__ partCnt,
                                               unsigned short* __restrict__ esrc, int* __restrict__ cnt,
                                               float* __restrict__ dv) {
  __shared__ unsigned int c256[256];
  int p = blockIdx.x, t = threadIdx.x;
  c256[t] = 0u;
  __syncthreads();
  int m = min((int)partCnt[p], PCAP);
  for (int i = t; i < m; i += 256) {
    unsigned int e = pe[(size_t)p * PCAP + i];
    unsigned int local = e >> 17;
    unsigned int s = e & 0x1FFFFu;
    unsigned int slot = atomicAdd(&c256[local], 1u);
    int node = p * 256 + (int)local;
    if (slot < CAP) esrc[(size_t)node * CAP + slot] = (unsigned short)s;
  }
  __syncthreads();
  int node = p * 256 + t;
  if (node < N_NODES) {
    int c = (int)c256[t];
    cnt[node] = c;
    dv[node] = rsqrtf((float)(c + 1));
    int padded = min((c + 7) & ~7, CAP);          // pad bucket to multiple of 8
    for (int s = c; s < padded; ++s) esrc[(size_t)node * CAP + s] = (unsigned short)ZROW;
  }
}

// ---------------- edv: pre-gather per-edge-slot dinv (sequentializes agg's dv reads) ----------------
// edv[node*CAP+slot] = dv[esrc[node*CAP+slot]]; pad slots get dv[ZROW]=0. Bit-identical values.

__global__ __launch_bounds__(256) void k_edv(const unsigned short* __restrict__ esrc,
                                             const int* __restrict__ cnt,
                                             const float* __restrict__ dv,
                                             float* __restrict__ edv) {
  int node = blockIdx.x * 32 + (threadIdx.x >> 3);
  if (node >= N_NODES) return;
  int s0 = (threadIdx.x & 7) * 8;                 // this lane's 8 slots
  int padded = min((cnt[node] + 7) & ~7, CAP);
  if (s0 >= padded) return;                       // garbage slots never read downstream
  const unsigned short* eb = esrc + (size_t)node * CAP + s0;
  ushort4 a = *(const ushort4*)(eb);
  ushort4 b = *(const ushort4*)(eb + 4);
  float4 da, db;
  da.x = dv[min((int)a.x, ZROW)]; da.y = dv[min((int)a.y, ZROW)];
  da.z = dv[min((int)a.z, ZROW)]; da.w = dv[min((int)a.w, ZROW)];
  db.x = dv[min((int)b.x, ZROW)]; db.y = dv[min((int)b.y, ZROW)];
  db.z = dv[min((int)b.z, ZROW)]; db.w = dv[min((int)b.w, ZROW)];
  *(float4*)(edv + (size_t)node * CAP + s0)     = da;
  *(float4*)(edv + (size_t)node * CAP + s0 + 4) = db;
}

// ---------------- agg1 by dim-slab (NSLAB=2, 16 lanes/node, sequential edv) ----------------
// slab = bid / NBLK. 16 lanes per node: lane loads ushort4 (8B); group covers 128 B row-slab.
// Inner loop: 2 broadcast idx loads + 2 broadcast edv float4 loads + 8 row gathers.

__global__ __launch_bounds__(256) void k_agg_slab(const unsigned short* __restrict__ hs,
                                                  const int* __restrict__ cnt,
                                                  const float* __restrict__ dv,
                                                  const unsigned short* __restrict__ esrc,
                                                  const float* __restrict__ edv,
                                                  const float* __restrict__ bias,
                                                  unsigned short* __restrict__ outh,
                                                  unsigned short* __restrict__ outl) {
  int bid = blockIdx.x;
  int slab = bid / NBLK;
  int nb = bid % NBLK;
  int grp = threadIdx.x >> 4, lane16 = threadIdx.x & 15;
  int node = nb * NODES_PER_BLK + grp;            // 3125*16 = 50000 exact

  const ushort4* h4 = (const ushort4*)(hs + (size_t)slab * PSTR);   // 16 x ushort4 per row-slab
  int deg = cnt[node];
  int end = min((deg + 7) & ~7, CAP);             // padded multiple of 8
  float di = dv[node];
  ushort4 hv = h4[(size_t)node * 16 + lane16];
  float ax = di * bf2f(hv.x), ay = di * bf2f(hv.y), az = di * bf2f(hv.z), aw = di * bf2f(hv.w);
  float bx = 0.f, by = 0.f, bz = 0.f, bw = 0.f;
  const unsigned short* eb = esrc + (size_t)node * CAP;
  const float* ev = edv + (size_t)node * CAP;
  for (int e = 0; e < end; e += 8) {
    ushort4 iA = *(const ushort4*)(eb + e);       // broadcast within group
    ushort4 iB = *(const ushort4*)(eb + e + 4);
    float4 dA = *(const float4*)(ev + e);         // sequential, broadcast within group
    float4 dB = *(const float4*)(ev + e + 4);
    ushort4 v0 = h4[(size_t)iA.x * 16 + lane16];
    ushort4 v1 = h4[(size_t)iA.y * 16 + lane16];
    ushort4 v2 = h4[(size_t)iA.z * 16 + lane16];
    ushort4 v3 = h4[(size_t)iA.w * 16 + lane16];
    ushort4 v4 = h4[(size_t)iB.x * 16 + lane16];
    ushort4 v5 = h4[(size_t)iB.y * 16 + lane16];
    ushort4 v6 = h4[(size_t)iB.z * 16 + lane16];
    ushort4 v7 = h4[(size_t)iB.w * 16 + lane16];
    ax = fmaf(dA.x, bf2f(v0.x), ax); ay = fmaf(dA.x, bf2f(v0.y), ay); az = fmaf(dA.x, bf2f(v0.z), az); aw = fmaf(dA.x, bf2f(v0.w), aw);
    bx = fmaf(dA.y, bf2f(v1.x), bx); by = fmaf(dA.y, bf2f(v1.y), by); bz = fmaf(dA.y, bf2f(v1.z), bz); bw = fmaf(dA.y, bf2f(v1.w), bw);
    ax = fmaf(dA.z, bf2f(v2.x), ax); ay = fmaf(dA.z, bf2f(v2.y), ay); az = fmaf(dA.z, bf2f(v2.z), az); aw = fmaf(dA.z, bf2f(v2.w), aw);
    bx = fmaf(dA.w, bf2f(v3.x), bx); by = fmaf(dA.w, bf2f(v3.y), by); bz = fmaf(dA.w, bf2f(v3.z), bz); bw = fmaf(dA.w, bf2f(v3.w), bw);
    ax = fmaf(dB.x, bf2f(v4.x), ax); ay = fmaf(dB.x, bf2f(v4.y), ay); az = fmaf(dB.x, bf2f(v4.z), az); aw = fmaf(dB.x, bf2f(v4.w), aw);
    bx = fmaf(dB.y, bf2f(v5.x), bx); by = fmaf(dB.y, bf2f(v5.y), by); bz = fmaf(dB.y, bf2f(v5.z), bz); bw = fmaf(dB.y, bf2f(v5.w), bw);
    ax = fmaf(dB.z, bf2f(v6.x), ax); ay = fmaf(dB.z, bf2f(v6.y), ay); az = fmaf(dB.z, bf2f(v6.z), az); aw = fmaf(dB.z, bf2f(v6.w), aw);
    bx = fmaf(dB.w, bf2f(v7.x), bx); by = fmaf(dB.w, bf2f(v7.y), by); bz = fmaf(dB.w, bf2f(v7.z), bz); bw = fmaf(dB.w, bf2f(v7.w), bw);
  }
  ax += bx; ay += by; az += bz; aw += bw;
  int base4 = slab * 16 + lane16;
  float4 bb = ((const float4*)bias)[base4];
  float vx = fmaf(di, ax, bb.x), vy = fmaf(di, ay, bb.y);
  float vz = fmaf(di, az, bb.z), vw = fmaf(di, aw, bb.w);
  ushort4 hi4, lo4;
  hi4.x = f2bf(vx); lo4.x = f2bf(vx - bf2f(hi4.x));
  hi4.y = f2bf(vy); lo4.y = f2bf(vy - bf2f(hi4.y));
  hi4.z = f2bf(vz); lo4.z = f2bf(vz - bf2f(hi4.z));
  hi4.w = f2bf(vw); lo4.w = f2bf(vw - bf2f(hi4.w));
  ((ushort4*)outh)[(size_t)node * 32 + base4] = hi4;
  ((ushort4*)outl)[(size_t)node * 32 + base4] = lo4;
}

// ---------------- gemm2: A from hi/lo planes, 3-term, bf16 out (row-major) ----------------

__global__ __launch_bounds__(256) void k_gemm_hl(const unsigned short* __restrict__ xh,
                                                 const unsigned short* __restrict__ xl,
                                                 const unsigned short* __restrict__ Wth,
                                                 const unsigned short* __restrict__ Wtl,
                                                 unsigned short* __restrict__ out, int nrows) {
  int wave = threadIdx.x >> 6, lane = threadIdx.x & 63;
  int l15 = lane & 15, quad = lane >> 4;
  int r0 = blockIdx.x * 128 + wave * 32;
  f32x4 acc[2][8];
  #pragma unroll
  for (int mt = 0; mt < 2; ++mt)
    #pragma unroll
    for (int nt = 0; nt < 8; ++nt) acc[mt][nt] = f32x4{0.f, 0.f, 0.f, 0.f};
  union U { uint4 u; bf16x8 h; };
  #pragma unroll
  for (int ks = 0; ks < 4; ++ks) {
    int k0 = ks * 32 + quad * 8;
    U ah[2], al[2];
    #pragma unroll
    for (int mt = 0; mt < 2; ++mt) {
      int row = r0 + mt * 16 + l15;
      row = (row < nrows) ? row : (nrows - 1);
      ah[mt].u = *(const uint4*)(xh + (size_t)row * DIM + k0);
      al[mt].u = *(const uint4*)(xl + (size_t)row * DIM + k0);
    }
    #pragma unroll
    for (int nt = 0; nt < 8; ++nt) {
      U bh, bl;
      bh.u = *(const uint4*)(Wth + (nt * 16 + l15) * DIM + k0);
      bl.u = *(const uint4*)(Wtl + (nt * 16 + l15) * DIM + k0);
      #pragma unroll
      for (int mt = 0; mt < 2; ++mt) {
        acc[mt][nt] = __builtin_amdgcn_mfma_f32_16x16x32_bf16(ah[mt].h, bh.h, acc[mt][nt], 0, 0, 0);
        acc[mt][nt] = __builtin_amdgcn_mfma_f32_16x16x32_bf16(al[mt].h, bh.h, acc[mt][nt], 0, 0, 0);
        acc[mt][nt] = __builtin_amdgcn_mfma_f32_16x16x32_bf16(ah[mt].h, bl.h, acc[mt][nt], 0, 0, 0);
      }
    }
  }
  #pragma unroll
  for (int mt = 0; mt < 2; ++mt)
    #pragma unroll
    for (int reg = 0; reg < 4; ++reg) {
      int row = r0 + mt * 16 + quad * 4 + reg;
      if (row < nrows) {
        #pragma unroll
        for (int nt = 0; nt < 8; ++nt)
          out[(size_t)row * DIM + nt * 16 + l15] = f2bf(acc[mt][nt][reg]);
      }
    }
}

// ---------------- full-row aggregation core (agg_batch; hbuf2 row-major, sequential edv) ----------------

static __device__ __forceinline__ float4 agg_compute(const unsigned short* __restrict__ h,
                                                     const int* __restrict__ cnt,
                                                     const float* __restrict__ dv,
                                                     const unsigned short* __restrict__ esrc,
                                                     const float* __restrict__ edv,
                                                     const float* __restrict__ bias,
                                                     int node, int lane) {
  const ushort4* h4 = (const ushort4*)h;
  int deg = cnt[node];
  int end = min((deg + 7) & ~7, CAP);              // padded length, multiple of 8
  float di = dv[node];
  ushort4 hv = h4[(size_t)node * 32 + lane];
  float ax = di * bf2f(hv.x), ay = di * bf2f(hv.y), az = di * bf2f(hv.z), aw = di * bf2f(hv.w);
  float bx = 0.f, by = 0.f, bz = 0.f, bw = 0.f;
  const unsigned short* eb = esrc + (size_t)node * CAP;
  const float* ev = edv + (size_t)node * CAP;
  for (int e = 0; e < end; e += 8) {
    ushort4 iA = *(const ushort4*)(eb + e);
    ushort4 iB = *(const ushort4*)(eb + e + 4);
    float4 dA = *(const float4*)(ev + e);
    float4 dB = *(const float4*)(ev + e + 4);
    ushort4 v0 = h4[(size_t)iA.x * 32 + lane];
    ushort4 v1 = h4[(size_t)iA.y * 32 + lane];
    ushort4 v2 = h4[(size_t)iA.z * 32 + lane];
    ushort4 v3 = h4[(size_t)iA.w * 32 + lane];
    ushort4 v4 = h4[(size_t)iB.x * 32 + lane];
    ushort4 v5 = h4[(size_t)iB.y * 32 + lane];
    ushort4 v6 = h4[(size_t)iB.z * 32 + lane];
    ushort4 v7 = h4[(size_t)iB.w * 32 + lane];
    ax = fmaf(dA.x, bf2f(v0.x), ax); ay = fmaf(dA.x, bf2f(v0.y), ay); az = fmaf(dA.x, bf2f(v0.z), az); aw = fmaf(dA.x, bf2f(v0.w), aw);
    bx = fmaf(dA.y, bf2f(v1.x), bx); by = fmaf(dA.y, bf2f(v1.y), by); bz = fmaf(dA.y, bf2f(v1.z), bz); bw = fmaf(dA.y, bf2f(v1.w), bw);
    ax = fmaf(dA.z, bf2f(v2.x), ax); ay = fmaf(dA.z, bf2f(v2.y), ay); az = fmaf(dA.z, bf2f(v2.z), az); aw = fmaf(dA.z, bf2f(v2.w), aw);
    bx = fmaf(dA.w, bf2f(v3.x), bx); by = fmaf(dA.w, bf2f(v3.y), by); bz = fmaf(dA.w, bf2f(v3.z), bz); bw = fmaf(dA.w, bf2f(v3.w), bw);
    ax = fmaf(dB.x, bf2f(v4.x), ax); ay = fmaf(dB.x, bf2f(v4.y), ay); az = fmaf(dB.x, bf2f(v4.z), az); aw = fmaf(dB.x, bf2f(v4.w), aw);
    bx = fmaf(dB.y, bf2f(v5.x), bx); by = fmaf(dB.y, bf2f(v5.y), by); bz = fmaf(dB.y, bf2f(v5.z), bz); bw = fmaf(dB.y, bf2f(v5.w), bw);
    ax = fmaf(dB.z, bf2f(v6.x), ax); ay = fmaf(dB.z, bf2f(v6.y), ay); az = fmaf(dB.z, bf2f(v6.z), az); aw = fmaf(dB.z, bf2f(v6.w), aw);
    bx = fmaf(dB.w, bf2f(v7.x), bx); by = fmaf(dB.w, bf2f(v7.y), by); bz = fmaf(dB.w, bf2f(v7.z), bz); bw = fmaf(dB.w, bf2f(v7.w), bw);
  }
  ax += bx; ay += by; az += bz; aw += bw;
  float4 bb = ((const float4*)bias)[lane];
  float4 v;
  v.x = fmaf(di, ax, bb.x); v.y = fmaf(di, ay, bb.y);
  v.z = fmaf(di, az, bb.z); v.w = fmaf(di, aw, bb.w);
  return v;
}

// ---------------- agg2 at batch positions only ----------------
// head rows -> fp32 plane pf[BATCH][128]; tail rows -> bf16 hi plane pth[BATCH][128]

__global__ __launch_bounds__(256) void k_agg_batch(const unsigned short* __restrict__ h,
                                                   const int* __restrict__ cnt,
                                                   const float* __restrict__ dv,
                                                   const unsigned short* __restrict__ esrc,
                                                   const float* __restrict__ edv,
                                                   const float* __restrict__ bias,
                                                   const int* __restrict__ head,
                                                   const int* __restrict__ tail,
                                                   float* __restrict__ pf,
                                                   unsigned short* __restrict__ pth) {
  int pos = blockIdx.x * 8 + (threadIdx.x >> 5);
  if (pos >= 2 * BATCH) return;
  int lane = threadIdx.x & 31;
  int node = (pos < BATCH) ? head[pos] : tail[pos - BATCH];
  float4 v = agg_compute(h, cnt, dv, esrc, edv, bias, node, lane);
  if (pos < BATCH) {
    ((float4*)pf)[(size_t)pos * 32 + lane] = v;
  } else {
    ushort4 hi4 = { f2bf(v.x), f2bf(v.y), f2bf(v.z), f2bf(v.w) };
    ((ushort4*)pth)[(size_t)(pos - BATCH) * 32 + lane] = hi4;
  }
}

// ---------------- predict via MFMA: tail (bf16) @ Q_r, dot with head (fp32) ----------------

__global__ __launch_bounds__(256) void k_predict_mfma(const float* __restrict__ pf,
                                                      const unsigned short* __restrict__ pth,
                                                      const unsigned short* __restrict__ Qbf,
                                                      float* __restrict__ out) {
  __shared__ __align__(16) unsigned short Qs[DIM * QPAD];
  int r = blockIdx.y;
  const unsigned short* Qr = Qbf + (size_t)r * DIM * DIM;
  for (int i = threadIdx.x; i < DIM * DIM / 8; i += 256) {
    int d = i >> 4, c = (i & 15) * 8;
    uint4 v = ((const uint4*)Qr)[i];
    *(uint4*)(&Qs[d * QPAD + c]) = v;
  }
  __syncthreads();
  int wave = threadIdx.x >> 6, lane = threadIdx.x & 63;
  int l15 = lane & 15, quad = lane >> 4;
  int bbase = blockIdx.x * 128 + wave * 32;
  int t0 = bbase + l15;                    // tail plane rows (coalesced, no gather)
  int t1 = bbase + 16 + l15;

  f32x4 acc[2][8];
  #pragma unroll
  for (int m = 0; m < 2; ++m)
    #pragma unroll
    for (int n = 0; n < 8; ++n) acc[m][n] = f32x4{0.f, 0.f, 0.f, 0.f};

  union U { uint4 u; bf16x8 h; };
  #pragma unroll
  for (int ks = 0; ks < 4; ++ks) {
    int eoff = ks * 32 + quad * 8;
    U a0, a1;
    a0.u = *(const uint4*)(pth + (size_t)t0 * DIM + eoff);
    a1.u = *(const uint4*)(pth + (size_t)t1 * DIM + eoff);
    #pragma unroll
    for (int nt = 0; nt < 8; ++nt) {
      U b; b.u = *(const uint4*)(&Qs[(nt * 16 + l15) * QPAD + eoff]);
      acc[0][nt] = __builtin_amdgcn_mfma_f32_16x16x32_bf16(a0.h, b.h, acc[0][nt], 0, 0, 0);
      acc[1][nt] = __builtin_amdgcn_mfma_f32_16x16x32_bf16(a1.h, b.h, acc[1][nt], 0, 0, 0);
    }
  }

  #pragma unroll
  for (int m = 0; m < 2; ++m) {
    #pragma unroll
    for (int reg = 0; reg < 4; ++reg) {
      int bl = bbase + m * 16 + quad * 4 + reg;             // batch index == head plane row
      float s = 0.f;
      #pragma unroll
      for (int nt = 0; nt < 8; ++nt)
        s += pf[(size_t)bl * DIM + nt * 16 + l15] * acc[m][nt][reg];   // head = fp32 plane
      #pragma unroll
      for (int off = 1; off < 16; off <<= 1) s += __shfl_xor(s, off, 64);
      if (l15 == 0) out[(size_t)bl * N_REL + r] = s;
    }
  }
}

// ---------------- launch ----------------

extern "C" void kernel_launch(void* const* d_in, const int* in_sizes, int n_in,
                              void* d_out, int out_size, void* d_ws, size_t ws_size,
                              hipStream_t stream) {
  (void)in_sizes; (void)n_in; (void)out_size; (void)ws_size;
  const float* init_emb = (const float*)d_in[0];
  const float* W1  = (const float*)d_in[1];
  const float* b1  = (const float*)d_in[2];
  const float* W2  = (const float*)d_in[3];
  const float* b2  = (const float*)d_in[4];
  const float* Rel = (const float*)d_in[5];
  const float* M   = (const float*)d_in[6];
  const int* head  = (const int*)d_in[7];
  const int* tail  = (const int*)d_in[8];
  const int* src   = (const int*)d_in[9];
  const int* dst   = src + N_EDGES;
  float* out = (float*)d_out;

  char* p = (char*)d_ws;
  auto alloc = [&](size_t bytes) { char* q = p; p += (bytes + 511) & ~(size_t)511; return q; };
  unsigned int* pcnt = (unsigned int*)alloc((size_t)NP * 4);                   // atomic partition counters
  unsigned int* pe = (unsigned int*)alloc((size_t)NP * PCAP * 4);              // 6.4 MB packed edges
  int*   cnt = (int*)alloc((size_t)N_NODES * 4);
  float* dv  = (float*)alloc((size_t)(N_NODES + 1) * 4);                       // +1 sentinel
  unsigned short* esrc = (unsigned short*)alloc((size_t)N_NODES * CAP * 2);    // 6.4 MB u16 buckets
  float* edv = (float*)alloc((size_t)N_NODES * CAP * 4);                       // 12.8 MB per-slot dinv
  unsigned short* hs    = (unsigned short*)alloc((size_t)NSLAB * PSTR * 2);    // slab-major h1 (+zero row)
  unsigned short* hbuf2 = (unsigned short*)alloc((size_t)(N_NODES + 1) * DIM * 2);  // +1 zero row
  unsigned short* aggh  = (unsigned short*)alloc((size_t)N_NODES * DIM * 2);   // agg1 hi plane
  unsigned short* aggl  = (unsigned short*)alloc((size_t)N_NODES * DIM * 2);   // agg1 lo plane
  float*          pf    = (float*)alloc((size_t)BATCH * DIM * 4);              // head plane fp32
  unsigned short* pth   = (unsigned short*)alloc((size_t)BATCH * DIM * 2);     // tail plane bf16 hi
  unsigned short* Qbf   = (unsigned short*)alloc((size_t)N_REL * DIM * DIM * 2);
  unsigned short* W1th  = (unsigned short*)alloc((size_t)DIM * DIM * 2);
  unsigned short* W1tl  = (unsigned short*)alloc((size_t)DIM * DIM * 2);
  unsigned short* W2th  = (unsigned short*)alloc((size_t)DIM * DIM * 2);
  unsigned short* W2tl  = (unsigned short*)alloc((size_t)DIM * DIM * 2);
  unsigned short* Mth   = (unsigned short*)alloc((size_t)DIM * DIM * 2);

  // 0: weight prep + sentinel zeroing + pcnt zero
  k_prep<<<DIM * DIM / 256, 256, 0, stream>>>(W1, W2, M, W1th, W1tl, W2th, W2tl, Mth,
                                              hs, hbuf2, dv, pcnt);
  // 1: single-pass edge build (hist -> reserve -> scatter) || decoder TQ || gemm1
  k_mega1<<<EB + G_TQ + G_GEMM, 256, 0, stream>>>(src, dst, pcnt, pe, Rel, Mth, Qbf,
                                                  init_emb, W1th, W1tl, hs);
  // 2: per-partition bucket fill (u16, pad-to-8) -> esrc + cnt + dinv
  k_build<<<NP, 256, 0, stream>>>(pe, pcnt, esrc, cnt, dv);
  // 3: pre-gather per-slot dinv -> edv (sequentializes agg's dv reads)
  k_edv<<<(N_NODES + 31) / 32, 256, 0, stream>>>(esrc, cnt, dv, edv);
  // 4: agg1 by dim-slab (2 slabs, 16 lanes/node, sequential edv) -> hi/lo planes
  k_agg_slab<<<NSLAB * NBLK, 256, 0, stream>>>(hs, cnt, dv, esrc, edv, b1, aggh, aggl);
  // 5: gemm2 from planes
  k_gemm_hl<<<(N_NODES + 127) / 128, 256, 0, stream>>>(aggh, aggl, W2th, W2tl, hbuf2, N_NODES);
  // 6: agg2 only at batch positions -> compact planes (head fp32, tail bf16)
  k_agg_batch<<<(2 * BATCH + 7) / 8, 256, 0, stream>>>(hbuf2, cnt, dv, esrc, edv, b2, head, tail, pf, pth);
  // 7: predict (coalesced reads from compact planes)
  k_predict_mfma<<<dim3(BATCH / 128, N_REL), 256, 0, stream>>>(pf, pth, Qbf, out);
}

// Round 10
// 213.464 us; speedup vs baseline: 1.1317x; 1.0150x over previous
//
#include <hip/hip_runtime.h>

#define N_NODES 50000
#define N_EDGES 800000
#define DIM 128
#define N_REL 86
#define BATCH 2048
#define CAP 64               // per-node bucket capacity; max deg ~45 for Poisson(16)
#define ZROW N_NODES         // sentinel row: zeroed embedding row, dv[ZROW]=0 (fits u16)

#define NP 196               // partitions by dst>>8 (256 nodes each; ceil(50000/256))
#define EB 196               // edge blocks for build (4096 edges each)
#define PCAP 8192            // partition edge capacity (mean 4096, sigma 64)

#define NSLAB 2              // 64-dim slabs; slab-major planes, 6.4 MB each
#define PSTR ((size_t)(N_NODES + 1) * 64)                       // ushorts per slab plane

using bf16x8 = __attribute__((ext_vector_type(8))) short;
using f32x4  = __attribute__((ext_vector_type(4))) float;

// float -> bf16 round-to-nearest-even (finite inputs)
static __device__ __forceinline__ unsigned short f2bf(float f) {
  union { float f; unsigned int i; } v; v.f = f;
  unsigned int x = v.i;
  unsigned int r = x + 0x7FFFu + ((x >> 16) & 1u);
  return (unsigned short)(r >> 16);
}
static __device__ __forceinline__ float bf2f(unsigned short u) {
  union { unsigned int i; float f; } v;
  v.i = ((unsigned int)u) << 16;
  return v.f;
}

#define G_TQ    172           // 86 relations x 2 d-blocks
#define G_GEMM  391           // ceil(50000/128)
#define TPAD 136              // 128+8 bf16: 272 B row stride -> 2-way bank alias (free)
#define QPAD 136
#define APAD 136

// ---------------- kernel 0: weight prep + sentinel-row zeroing + pcnt zero ----------------

__global__ __launch_bounds__(256) void k_prep(const float* __restrict__ W1, const float* __restrict__ W2,
                                              const float* __restrict__ M,
                                              unsigned short* __restrict__ W1th, unsigned short* __restrict__ W1tl,
                                              unsigned short* __restrict__ W2th, unsigned short* __restrict__ W2tl,
                                              unsigned short* __restrict__ Mth,
                                              unsigned short* __restrict__ hs,
                                              unsigned short* __restrict__ hbuf2,
                                              float* __restrict__ dv,
                                              unsigned int* __restrict__ pcnt) {
  int g = blockIdx.x * 256 + threadIdx.x;          // 16384 threads = DIM*DIM
  if (g < NP) pcnt[g] = 0u;                        // partition atomic counters
  // zero sentinel rows (gather pads resolve to ZROW; must be 0.0 not garbage/NaN)
  if (g < 32) {                                    // 2 slab planes x 16 ushort4
    ushort4 z = {0, 0, 0, 0};
    ((ushort4*)(hs + (size_t)(g >> 4) * PSTR))[(size_t)ZROW * 16 + (g & 15)] = z;
  }
  if (g >= 32 && g < 64) {                         // hbuf2 row (32 ushort4)
    ushort4 z = {0, 0, 0, 0};
    ((ushort4*)hbuf2)[(size_t)ZROW * 32 + (g - 32)] = z;
  }
  if (g == 64) dv[ZROW] = 0.f;
  int k = g >> 7, n = g & 127;
  int t = n * DIM + k;
  float w1 = W1[g];
  unsigned short h1 = f2bf(w1);
  W1th[t] = h1;
  W1tl[t] = f2bf(w1 - bf2f(h1));
  float w2 = W2[g];
  unsigned short h2 = f2bf(w2);
  W2th[t] = h2;
  W2tl[t] = f2bf(w2 - bf2f(h2));
  Mth[t] = f2bf(M[g]);
}

// ---------------- mega1: single-pass edge build (regs held across hist -> reserve -> scatter)
//                         ||  decoder TQ  ||  gemm1 (slab-major out) ----------------
// pe entry: (dst & 255) << 17 | src     (src < 50000 < 2^17)

__global__ __launch_bounds__(256) void k_mega1(const int* __restrict__ src, const int* __restrict__ dst,
                                               unsigned int* __restrict__ pcnt,
                                               unsigned int* __restrict__ pe,
                                               const float* __restrict__ Rel,
                                               const unsigned short* __restrict__ Mth,
                                               unsigned short* __restrict__ Qbf,
                                               const float* __restrict__ x,
                                               const unsigned short* __restrict__ W1th,
                                               const unsigned short* __restrict__ W1tl,
                                               unsigned short* __restrict__ hs) {
  __shared__ __align__(16) unsigned char smem[64 * TPAD * 2];   // max(hist 784B, Ts 17408B)
  int bid = blockIdx.x;
  union U { uint4 u; bf16x8 h; };

  if (bid < EB) {
    unsigned int* hist = (unsigned int*)smem;
    int t = threadIdx.x;
    if (t < NP) hist[t] = 0u;
    __syncthreads();
    // ---- load edges ONCE into registers, histogram ----
    int4 sA[4], dA[4];
    #pragma unroll
    for (int j = 0; j < 4; ++j) {
      int i0 = bid * 4096 + j * 1024 + t * 4;
      if (i0 < N_EDGES) {
        sA[j] = *(const int4*)(src + i0);
        dA[j] = *(const int4*)(dst + i0);
        atomicAdd(&hist[dA[j].x >> 8], 1u);
        atomicAdd(&hist[dA[j].y >> 8], 1u);
        atomicAdd(&hist[dA[j].z >> 8], 1u);
        atomicAdd(&hist[dA[j].w >> 8], 1u);
      }
    }
    __syncthreads();
    // ---- reserve global ranges: one atomic per (block, bin) ----
    if (t < NP) {
      unsigned int c = hist[t];
      unsigned int base = c ? atomicAdd(&pcnt[t], c) : 0u;
      hist[t] = (unsigned int)t * PCAP + base;     // becomes this block's write cursor
    }
    __syncthreads();
    // ---- scatter from registers via LDS cursor ----
    #pragma unroll
    for (int j = 0; j < 4; ++j) {
      int i0 = bid * 4096 + j * 1024 + t * 4;
      if (i0 < N_EDGES) {
        int b0 = dA[j].x >> 8, b1 = dA[j].y >> 8, b2 = dA[j].z >> 8, b3 = dA[j].w >> 8;
        unsigned int p0 = atomicAdd(&hist[b0], 1u);
        unsigned int p1 = atomicAdd(&hist[b1], 1u);
        unsigned int p2 = atomicAdd(&hist[b2], 1u);
        unsigned int p3 = atomicAdd(&hist[b3], 1u);
        if (p0 < (unsigned int)(b0 + 1) * PCAP) pe[p0] = ((unsigned)(dA[j].x & 255) << 17) | (unsigned)sA[j].x;
        if (p1 < (unsigned int)(b1 + 1) * PCAP) pe[p1] = ((unsigned)(dA[j].y & 255) << 17) | (unsigned)sA[j].y;
        if (p2 < (unsigned int)(b2 + 1) * PCAP) pe[p2] = ((unsigned)(dA[j].z & 255) << 17) | (unsigned)sA[j].z;
        if (p3 < (unsigned int)(b3 + 1) * PCAP) pe[p3] = ((unsigned)(dA[j].w & 255) << 17) | (unsigned)sA[j].w;
      }
    }
    return;
  }

  int wave = threadIdx.x >> 6, lane = threadIdx.x & 63;
  int l15 = lane & 15, quad = lane >> 4;

  if (bid < EB + G_TQ) {
    // ---- decoder precompute: T_r = Rel_r @ M (LDS), Q_r = T_r @ Rel_r^T ----
    unsigned short* Ts = (unsigned short*)smem;
    int tb = bid - EB;                       // [0, 172)
    int r = tb >> 1, dblk = tb & 1;
    const float* Rr = Rel + (size_t)r * DIM * DIM;
    unsigned short* Qr = Qbf + (size_t)r * DIM * DIM;
    int dw = dblk * 64 + wave * 16;
    f32x4 acc[8];
    #pragma unroll
    for (int nt = 0; nt < 8; ++nt) acc[nt] = f32x4{0.f, 0.f, 0.f, 0.f};
    #pragma unroll
    for (int ks = 0; ks < 4; ++ks) {
      int k0 = ks * 32 + quad * 8;
      const float* ap = Rr + (size_t)(dw + l15) * DIM + k0;
      float av[8];
      *(float4*)(av)     = *(const float4*)(ap);
      *(float4*)(av + 4) = *(const float4*)(ap + 4);
      bf16x8 a;
      #pragma unroll
      for (int j = 0; j < 8; ++j) a[j] = (short)f2bf(av[j]);
      #pragma unroll
      for (int nt = 0; nt < 8; ++nt) {
        U b; b.u = *(const uint4*)(Mth + (nt * 16 + l15) * DIM + k0);
        acc[nt] = __builtin_amdgcn_mfma_f32_16x16x32_bf16(a, b.h, acc[nt], 0, 0, 0);
      }
    }
    #pragma unroll
    for (int nt = 0; nt < 8; ++nt)
      #pragma unroll
      for (int reg = 0; reg < 4; ++reg)
        Ts[(wave * 16 + quad * 4 + reg) * TPAD + nt * 16 + l15] = f2bf(acc[nt][reg]);
    __syncthreads();
    f32x4 qacc[8];
    #pragma unroll
    for (int nt = 0; nt < 8; ++nt) qacc[nt] = f32x4{0.f, 0.f, 0.f, 0.f};
    #pragma unroll
    for (int ks = 0; ks < 4; ++ks) {
      int k0 = ks * 32 + quad * 8;
      U a; a.u = *(const uint4*)(Ts + (wave * 16 + l15) * TPAD + k0);
      #pragma unroll
      for (int nt = 0; nt < 8; ++nt) {
        const float* bp = Rr + (size_t)(nt * 16 + l15) * DIM + k0;
        float bv[8];
        *(float4*)(bv)     = *(const float4*)(bp);
        *(float4*)(bv + 4) = *(const float4*)(bp + 4);
        bf16x8 b;
        #pragma unroll
        for (int j = 0; j < 8; ++j) b[j] = (short)f2bf(bv[j]);
        qacc[nt] = __builtin_amdgcn_mfma_f32_16x16x32_bf16(a.h, b, qacc[nt], 0, 0, 0);
      }
    }
    #pragma unroll
    for (int nt = 0; nt < 8; ++nt)
      #pragma unroll
      for (int reg = 0; reg < 4; ++reg)
        Qr[(size_t)(dw + quad * 4 + reg) * DIM + nt * 16 + l15] = f2bf(qacc[nt][reg]);
    return;
  }

  // ---- node GEMM layer 1: hs = slab-major(x @ W1) (hi/lo 3-term, bf16 out) ----
  int r0 = (bid - EB - G_TQ) * 128 + wave * 32;
  f32x4 acc[2][8];
  #pragma unroll
  for (int mt = 0; mt < 2; ++mt)
    #pragma unroll
    for (int nt = 0; nt < 8; ++nt) acc[mt][nt] = f32x4{0.f, 0.f, 0.f, 0.f};
  #pragma unroll
  for (int ks = 0; ks < 4; ++ks) {
    int k0 = ks * 32 + quad * 8;
    bf16x8 ah[2], al[2];
    #pragma unroll
    for (int mt = 0; mt < 2; ++mt) {
      int row = r0 + mt * 16 + l15;
      row = (row < N_NODES) ? row : (N_NODES - 1);
      const float* xp = x + (size_t)row * DIM + k0;
      float xv[8];
      *(float4*)(xv)     = *(const float4*)(xp);
      *(float4*)(xv + 4) = *(const float4*)(xp + 4);
      #pragma unroll
      for (int j = 0; j < 8; ++j) {
        unsigned short h = f2bf(xv[j]);
        ah[mt][j] = (short)h;
        al[mt][j] = (short)f2bf(xv[j] - bf2f(h));
      }
    }
    #pragma unroll
    for (int nt = 0; nt < 8; ++nt) {
      U bh, bl;
      bh.u = *(const uint4*)(W1th + (nt * 16 + l15) * DIM + k0);
      bl.u = *(const uint4*)(W1tl + (nt * 16 + l15) * DIM + k0);
      #pragma unroll
      for (int mt = 0; mt < 2; ++mt) {
        acc[mt][nt] = __builtin_amdgcn_mfma_f32_16x16x32_bf16(ah[mt], bh.h, acc[mt][nt], 0, 0, 0);
        acc[mt][nt] = __builtin_amdgcn_mfma_f32_16x16x32_bf16(al[mt], bh.h, acc[mt][nt], 0, 0, 0);
        acc[mt][nt] = __builtin_amdgcn_mfma_f32_16x16x32_bf16(ah[mt], bl.h, acc[mt][nt], 0, 0, 0);
      }
    }
  }
  #pragma unroll
  for (int mt = 0; mt < 2; ++mt)
    #pragma unroll
    for (int reg = 0; reg < 4; ++reg) {
      int row = r0 + mt * 16 + quad * 4 + reg;
      if (row < N_NODES) {
        #pragma unroll
        for (int nt = 0; nt < 8; ++nt)
          hs[(size_t)(nt >> 2) * PSTR + (size_t)row * 64 + (nt & 3) * 16 + l15] = f2bf(acc[mt][nt][reg]);
      }
    }
}

// ---------------- build: per-partition bucket fill (u16) + pad-to-8 + cnt + dinv ----------------

__global__ __launch_bounds__(256) void k_build(const unsigned int* __restrict__ pe,
                                               const unsigned int* __restrict__ partCnt,
                                               unsigned short* __restrict__ esrc, int* __restrict__ cnt,
                                               float* __restrict__ dv) {
  __shared__ unsigned int c256[256];
  int p = blockIdx.x, t = threadIdx.x;
  c256[t] = 0u;
  __syncthreads();
  int m = min((int)partCnt[p], PCAP);
  for (int i = t; i < m; i += 256) {
    unsigned int e = pe[(size_t)p * PCAP + i];
    unsigned int local = e >> 17;
    unsigned int s = e & 0x1FFFFu;
    unsigned int slot = atomicAdd(&c256[local], 1u);
    int node = p * 256 + (int)local;
    if (slot < CAP) esrc[(size_t)node * CAP + slot] = (unsigned short)s;
  }
  __syncthreads();
  int node = p * 256 + t;
  if (node < N_NODES) {
    int c = (int)c256[t];
    cnt[node] = c;
    dv[node] = rsqrtf((float)(c + 1));
    int padded = min((c + 7) & ~7, CAP);          // pad bucket to multiple of 8
    for (int s = c; s < padded; ++s) esrc[(size_t)node * CAP + s] = (unsigned short)ZROW;
  }
}

// ---------------- edv: pre-gather per-edge-slot dinv (sequentializes agg's dv reads) ----------------

__global__ __launch_bounds__(256) void k_edv(const unsigned short* __restrict__ esrc,
                                             const int* __restrict__ cnt,
                                             const float* __restrict__ dv,
                                             float* __restrict__ edv) {
  int node = blockIdx.x * 32 + (threadIdx.x >> 3);
  if (node >= N_NODES) return;
  int s0 = (threadIdx.x & 7) * 8;                 // this lane's 8 slots
  int padded = min((cnt[node] + 7) & ~7, CAP);
  if (s0 >= padded) return;                       // garbage slots never read downstream
  const unsigned short* eb = esrc + (size_t)node * CAP + s0;
  ushort4 a = *(const ushort4*)(eb);
  ushort4 b = *(const ushort4*)(eb + 4);
  float4 da, db;
  da.x = dv[min((int)a.x, ZROW)]; da.y = dv[min((int)a.y, ZROW)];
  da.z = dv[min((int)a.z, ZROW)]; da.w = dv[min((int)a.w, ZROW)];
  db.x = dv[min((int)b.x, ZROW)]; db.y = dv[min((int)b.y, ZROW)];
  db.z = dv[min((int)b.z, ZROW)]; db.w = dv[min((int)b.w, ZROW)];
  *(float4*)(edv + (size_t)node * CAP + s0)     = da;
  *(float4*)(edv + (size_t)node * CAP + s0 + 4) = db;
}

// ---------------- fused agg1 + gemm2: 16 nodes/block; 32 lanes/node (16 per slab plane);
//                  each edge visited ONCE; then MFMA @ W2 from LDS ----------------

__global__ __launch_bounds__(256) void k_agg_gemm2(const unsigned short* __restrict__ hs,
                                                   const int* __restrict__ cnt,
                                                   const float* __restrict__ dv,
                                                   const unsigned short* __restrict__ esrc,
                                                   const float* __restrict__ edv,
                                                   const float* __restrict__ bias,
                                                   const unsigned short* __restrict__ Wth,
                                                   const unsigned short* __restrict__ Wtl,
                                                   unsigned short* __restrict__ out) {
  __shared__ __align__(16) unsigned short Ah[16 * APAD];
  __shared__ __align__(16) unsigned short Al[16 * APAD];
  int warp = threadIdx.x >> 5, lane32 = threadIdx.x & 31;
  int half = lane32 >> 4, lane16 = lane32 & 15;   // half selects slab plane
  int base = blockIdx.x * 16;                     // 3125 * 16 = 50000 exact

  const ushort4* h4 = (const ushort4*)(hs + (size_t)half * PSTR);   // 16 ushort4 per row-slab

  #pragma unroll
  for (int i = 0; i < 2; ++i) {
    int row = warp * 2 + i;
    int node = base + row;
    int deg = cnt[node];
    int end = min((deg + 7) & ~7, CAP);           // padded multiple of 8
    float di = dv[node];
    ushort4 hv = h4[(size_t)node * 16 + lane16];
    float ax = di * bf2f(hv.x), ay = di * bf2f(hv.y), az = di * bf2f(hv.z), aw = di * bf2f(hv.w);
    float bx = 0.f, by = 0.f, bz = 0.f, bw = 0.f;
    const unsigned short* eb = esrc + (size_t)node * CAP;
    const float* ev = edv + (size_t)node * CAP;
    for (int e = 0; e < end; e += 8) {
      ushort4 iA = *(const ushort4*)(eb + e);     // broadcast within 32-lane group
      ushort4 iB = *(const ushort4*)(eb + e + 4);
      float4 dA = *(const float4*)(ev + e);       // sequential, broadcast within group
      float4 dB = *(const float4*)(ev + e + 4);
      ushort4 v0 = h4[(size_t)iA.x * 16 + lane16];
      ushort4 v1 = h4[(size_t)iA.y * 16 + lane16];
      ushort4 v2 = h4[(size_t)iA.z * 16 + lane16];
      ushort4 v3 = h4[(size_t)iA.w * 16 + lane16];
      ushort4 v4 = h4[(size_t)iB.x * 16 + lane16];
      ushort4 v5 = h4[(size_t)iB.y * 16 + lane16];
      ushort4 v6 = h4[(size_t)iB.z * 16 + lane16];
      ushort4 v7 = h4[(size_t)iB.w * 16 + lane16];
      ax = fmaf(dA.x, bf2f(v0.x), ax); ay = fmaf(dA.x, bf2f(v0.y), ay); az = fmaf(dA.x, bf2f(v0.z), az); aw = fmaf(dA.x, bf2f(v0.w), aw);
      bx = fmaf(dA.y, bf2f(v1.x), bx); by = fmaf(dA.y, bf2f(v1.y), by); bz = fmaf(dA.y, bf2f(v1.z), bz); bw = fmaf(dA.y, bf2f(v1.w), bw);
      ax = fmaf(dA.z, bf2f(v2.x), ax); ay = fmaf(dA.z, bf2f(v2.y), ay); az = fmaf(dA.z, bf2f(v2.z), az); aw = fmaf(dA.z, bf2f(v2.w), aw);
      bx = fmaf(dA.w, bf2f(v3.x), bx); by = fmaf(dA.w, bf2f(v3.y), by); bz = fmaf(dA.w, bf2f(v3.z), bz); bw = fmaf(dA.w, bf2f(v3.w), bw);
      ax = fmaf(dB.x, bf2f(v4.x), ax); ay = fmaf(dB.x, bf2f(v4.y), ay); az = fmaf(dB.x, bf2f(v4.z), az); aw = fmaf(dB.x, bf2f(v4.w), aw);
      bx = fmaf(dB.y, bf2f(v5.x), bx); by = fmaf(dB.y, bf2f(v5.y), by); bz = fmaf(dB.y, bf2f(v5.z), bz); bw = fmaf(dB.y, bf2f(v5.w), bw);
      ax = fmaf(dB.z, bf2f(v6.x), ax); ay = fmaf(dB.z, bf2f(v6.y), ay); az = fmaf(dB.z, bf2f(v6.z), az); aw = fmaf(dB.z, bf2f(v6.w), aw);
      bx = fmaf(dB.w, bf2f(v7.x), bx); by = fmaf(dB.w, bf2f(v7.y), by); bz = fmaf(dB.w, bf2f(v7.z), bz); bw = fmaf(dB.w, bf2f(v7.w), bw);
    }
    ax += bx; ay += by; az += bz; aw += bw;
    float4 bb = ((const float4*)bias)[lane32];    // dims lane32*4..+3 = half*64 + lane16*4
    float vx = fmaf(di, ax, bb.x), vy = fmaf(di, ay, bb.y);
    float vz = fmaf(di, az, bb.z), vw = fmaf(di, aw, bb.w);
    ushort4 hi4, lo4;
    hi4.x = f2bf(vx); lo4.x = f2bf(vx - bf2f(hi4.x));
    hi4.y = f2bf(vy); lo4.y = f2bf(vy - bf2f(hi4.y));
    hi4.z = f2bf(vz); lo4.z = f2bf(vz - bf2f(hi4.z));
    hi4.w = f2bf(vw); lo4.w = f2bf(vw - bf2f(hi4.w));
    *(ushort4*)(&Ah[row * APAD + lane32 * 4]) = hi4;
    *(ushort4*)(&Al[row * APAD + lane32 * 4]) = lo4;
  }
  __syncthreads();

  // GEMM phase: 4 wave64s, each computes rows 0..15 x cols [wave*32, wave*32+32)
  int wave = threadIdx.x >> 6, l = threadIdx.x & 63;
  int l15 = l & 15, quad = l >> 4;
  union U { uint4 u; bf16x8 h; };
  f32x4 acc[2];
  #pragma unroll
  for (int nt = 0; nt < 2; ++nt) acc[nt] = f32x4{0.f, 0.f, 0.f, 0.f};
  #pragma unroll
  for (int ks = 0; ks < 4; ++ks) {
    int k0 = ks * 32 + quad * 8;
    U ah, al;
    ah.u = *(const uint4*)(&Ah[l15 * APAD + k0]);
    al.u = *(const uint4*)(&Al[l15 * APAD + k0]);
    #pragma unroll
    for (int nt = 0; nt < 2; ++nt) {
      int n0 = wave * 32 + nt * 16;
      U bh, bl;
      bh.u = *(const uint4*)(Wth + (n0 + l15) * DIM + k0);
      bl.u = *(const uint4*)(Wtl + (n0 + l15) * DIM + k0);
      acc[nt] = __builtin_amdgcn_mfma_f32_16x16x32_bf16(ah.h, bh.h, acc[nt], 0, 0, 0);
      acc[nt] = __builtin_amdgcn_mfma_f32_16x16x32_bf16(al.h, bh.h, acc[nt], 0, 0, 0);
      acc[nt] = __builtin_amdgcn_mfma_f32_16x16x32_bf16(ah.h, bl.h, acc[nt], 0, 0, 0);
    }
  }
  #pragma unroll
  for (int reg = 0; reg < 4; ++reg) {
    int row = base + quad * 4 + reg;
    #pragma unroll
    for (int nt = 0; nt < 2; ++nt)
      out[(size_t)row * DIM + wave * 32 + nt * 16 + l15] = f2bf(acc[nt][reg]);
  }
}

// ---------------- full-row aggregation core (agg_batch; hbuf2 row-major, sequential edv) ----------------

static __device__ __forceinline__ float4 agg_compute(const unsigned short* __restrict__ h,
                                                     const int* __restrict__ cnt,
                                                     const float* __restrict__ dv,
                                                     const unsigned short* __restrict__ esrc,
                                                     const float* __restrict__ edv,
                                                     const float* __restrict__ bias,
                                                     int node, int lane) {
  const ushort4* h4 = (const ushort4*)h;
  int deg = cnt[node];
  int end = min((deg + 7) & ~7, CAP);              // padded length, multiple of 8
  float di = dv[node];
  ushort4 hv = h4[(size_t)node * 32 + lane];
  float ax = di * bf2f(hv.x), ay = di * bf2f(hv.y), az = di * bf2f(hv.z), aw = di * bf2f(hv.w);
  float bx = 0.f, by = 0.f, bz = 0.f, bw = 0.f;
  const unsigned short* eb = esrc + (size_t)node * CAP;
  const float* ev = edv + (size_t)node * CAP;
  for (int e = 0; e < end; e += 8) {
    ushort4 iA = *(const ushort4*)(eb + e);
    ushort4 iB = *(const ushort4*)(eb + e + 4);
    float4 dA = *(const float4*)(ev + e);
    float4 dB = *(const float4*)(ev + e + 4);
    ushort4 v0 = h4[(size_t)iA.x * 32 + lane];
    ushort4 v1 = h4[(size_t)iA.y * 32 + lane];
    ushort4 v2 = h4[(size_t)iA.z * 32 + lane];
    ushort4 v3 = h4[(size_t)iA.w * 32 + lane];
    ushort4 v4 = h4[(size_t)iB.x * 32 + lane];
    ushort4 v5 = h4[(size_t)iB.y * 32 + lane];
    ushort4 v6 = h4[(size_t)iB.z * 32 + lane];
    ushort4 v7 = h4[(size_t)iB.w * 32 + lane];
    ax = fmaf(dA.x, bf2f(v0.x), ax); ay = fmaf(dA.x, bf2f(v0.y), ay); az = fmaf(dA.x, bf2f(v0.z), az); aw = fmaf(dA.x, bf2f(v0.w), aw);
    bx = fmaf(dA.y, bf2f(v1.x), bx); by = fmaf(dA.y, bf2f(v1.y), by); bz = fmaf(dA.y, bf2f(v1.z), bz); bw = fmaf(dA.y, bf2f(v1.w), bw);
    ax = fmaf(dA.z, bf2f(v2.x), ax); ay = fmaf(dA.z, bf2f(v2.y), ay); az = fmaf(dA.z, bf2f(v2.z), az); aw = fmaf(dA.z, bf2f(v2.w), aw);
    bx = fmaf(dA.w, bf2f(v3.x), bx); by = fmaf(dA.w, bf2f(v3.y), by); bz = fmaf(dA.w, bf2f(v3.z), bz); bw = fmaf(dA.w, bf2f(v3.w), bw);
    ax = fmaf(dB.x, bf2f(v4.x), ax); ay = fmaf(dB.x, bf2f(v4.y), ay); az = fmaf(dB.x, bf2f(v4.z), az); aw = fmaf(dB.x, bf2f(v4.w), aw);
    bx = fmaf(dB.y, bf2f(v5.x), bx); by = fmaf(dB.y, bf2f(v5.y), by); bz = fmaf(dB.y, bf2f(v5.z), bz); bw = fmaf(dB.y, bf2f(v5.w), bw);
    ax = fmaf(dB.z, bf2f(v6.x), ax); ay = fmaf(dB.z, bf2f(v6.y), ay); az = fmaf(dB.z, bf2f(v6.z), az); aw = fmaf(dB.z, bf2f(v6.w), aw);
    bx = fmaf(dB.w, bf2f(v7.x), bx); by = fmaf(dB.w, bf2f(v7.y), by); bz = fmaf(dB.w, bf2f(v7.z), bz); bw = fmaf(dB.w, bf2f(v7.w), bw);
  }
  ax += bx; ay += by; az += bz; aw += bw;
  float4 bb = ((const float4*)bias)[lane];
  float4 v;
  v.x = fmaf(di, ax, bb.x); v.y = fmaf(di, ay, bb.y);
  v.z = fmaf(di, az, bb.z); v.w = fmaf(di, aw, bb.w);
  return v;
}

// ---------------- agg2 at batch positions only ----------------
// head rows -> fp32 plane pf[BATCH][128]; tail rows -> bf16 hi plane pth[BATCH][128]

__global__ __launch_bounds__(256) void k_agg_batch(const unsigned short* __restrict__ h,
                                                   const int* __restrict__ cnt,
                                                   const float* __restrict__ dv,
                                                   const unsigned short* __restrict__ esrc,
                                                   const float* __restrict__ edv,
                                                   const float* __restrict__ bias,
                                                   const int* __restrict__ head,
                                                   const int* __restrict__ tail,
                                                   float* __restrict__ pf,
                                                   unsigned short* __restrict__ pth) {
  int pos = blockIdx.x * 8 + (threadIdx.x >> 5);
  if (pos >= 2 * BATCH) return;
  int lane = threadIdx.x & 31;
  int node = (pos < BATCH) ? head[pos] : tail[pos - BATCH];
  float4 v = agg_compute(h, cnt, dv, esrc, edv, bias, node, lane);
  if (pos < BATCH) {
    ((float4*)pf)[(size_t)pos * 32 + lane] = v;
  } else {
    ushort4 hi4 = { f2bf(v.x), f2bf(v.y), f2bf(v.z), f2bf(v.w) };
    ((ushort4*)pth)[(size_t)(pos - BATCH) * 32 + lane] = hi4;
  }
}

// ---------------- predict via MFMA: tail (bf16) @ Q_r, dot with head (fp32) ----------------

__global__ __launch_bounds__(256) void k_predict_mfma(const float* __restrict__ pf,
                                                      const unsigned short* __restrict__ pth,
                                                      const unsigned short* __restrict__ Qbf,
                                                      float* __restrict__ out) {
  __shared__ __align__(16) unsigned short Qs[DIM * QPAD];
  int r = blockIdx.y;
  const unsigned short* Qr = Qbf + (size_t)r * DIM * DIM;
  for (int i = threadIdx.x; i < DIM * DIM / 8; i += 256) {
    int d = i >> 4, c = (i & 15) * 8;
    uint4 v = ((const uint4*)Qr)[i];
    *(uint4*)(&Qs[d * QPAD + c]) = v;
  }
  __syncthreads();
  int wave = threadIdx.x >> 6, lane = threadIdx.x & 63;
  int l15 = lane & 15, quad = lane >> 4;
  int bbase = blockIdx.x * 128 + wave * 32;
  int t0 = bbase + l15;                    // tail plane rows (coalesced, no gather)
  int t1 = bbase + 16 + l15;

  f32x4 acc[2][8];
  #pragma unroll
  for (int m = 0; m < 2; ++m)
    #pragma unroll
    for (int n = 0; n < 8; ++n) acc[m][n] = f32x4{0.f, 0.f, 0.f, 0.f};

  union U { uint4 u; bf16x8 h; };
  #pragma unroll
  for (int ks = 0; ks < 4; ++ks) {
    int eoff = ks * 32 + quad * 8;
    U a0, a1;
    a0.u = *(const uint4*)(pth + (size_t)t0 * DIM + eoff);
    a1.u = *(const uint4*)(pth + (size_t)t1 * DIM + eoff);
    #pragma unroll
    for (int nt = 0; nt < 8; ++nt) {
      U b; b.u = *(const uint4*)(&Qs[(nt * 16 + l15) * QPAD + eoff]);
      acc[0][nt] = __builtin_amdgcn_mfma_f32_16x16x32_bf16(a0.h, b.h, acc[0][nt], 0, 0, 0);
      acc[1][nt] = __builtin_amdgcn_mfma_f32_16x16x32_bf16(a1.h, b.h, acc[1][nt], 0, 0, 0);
    }
  }

  #pragma unroll
  for (int m = 0; m < 2; ++m) {
    #pragma unroll
    for (int reg = 0; reg < 4; ++reg) {
      int bl = bbase + m * 16 + quad * 4 + reg;             // batch index == head plane row
      float s = 0.f;
      #pragma unroll
      for (int nt = 0; nt < 8; ++nt)
        s += pf[(size_t)bl * DIM + nt * 16 + l15] * acc[m][nt][reg];   // head = fp32 plane
      #pragma unroll
      for (int off = 1; off < 16; off <<= 1) s += __shfl_xor(s, off, 64);
      if (l15 == 0) out[(size_t)bl * N_REL + r] = s;
    }
  }
}

// ---------------- launch ----------------

extern "C" void kernel_launch(void* const* d_in, const int* in_sizes, int n_in,
                              void* d_out, int out_size, void* d_ws, size_t ws_size,
                              hipStream_t stream) {
  (void)in_sizes; (void)n_in; (void)out_size; (void)ws_size;
  const float* init_emb = (const float*)d_in[0];
  const float* W1  = (const float*)d_in[1];
  const float* b1  = (const float*)d_in[2];
  const float* W2  = (const float*)d_in[3];
  const float* b2  = (const float*)d_in[4];
  const float* Rel = (const float*)d_in[5];
  const float* M   = (const float*)d_in[6];
  const int* head  = (const int*)d_in[7];
  const int* tail  = (const int*)d_in[8];
  const int* src   = (const int*)d_in[9];
  const int* dst   = src + N_EDGES;
  float* out = (float*)d_out;

  char* p = (char*)d_ws;
  auto alloc = [&](size_t bytes) { char* q = p; p += (bytes + 511) & ~(size_t)511; return q; };
  unsigned int* pcnt = (unsigned int*)alloc((size_t)NP * 4);                   // atomic partition counters
  unsigned int* pe = (unsigned int*)alloc((size_t)NP * PCAP * 4);              // 6.4 MB packed edges
  int*   cnt = (int*)alloc((size_t)N_NODES * 4);
  float* dv  = (float*)alloc((size_t)(N_NODES + 1) * 4);                       // +1 sentinel
  unsigned short* esrc = (unsigned short*)alloc((size_t)N_NODES * CAP * 2);    // 6.4 MB u16 buckets
  float* edv = (float*)alloc((size_t)N_NODES * CAP * 4);                       // 12.8 MB per-slot dinv
  unsigned short* hs    = (unsigned short*)alloc((size_t)NSLAB * PSTR * 2);    // slab-major h1 (+zero row)
  unsigned short* hbuf2 = (unsigned short*)alloc((size_t)(N_NODES + 1) * DIM * 2);  // +1 zero row
  float*          pf    = (float*)alloc((size_t)BATCH * DIM * 4);              // head plane fp32
  unsigned short* pth   = (unsigned short*)alloc((size_t)BATCH * DIM * 2);     // tail plane bf16 hi
  unsigned short* Qbf   = (unsigned short*)alloc((size_t)N_REL * DIM * DIM * 2);
  unsigned short* W1th  = (unsigned short*)alloc((size_t)DIM * DIM * 2);
  unsigned short* W1tl  = (unsigned short*)alloc((size_t)DIM * DIM * 2);
  unsigned short* W2th  = (unsigned short*)alloc((size_t)DIM * DIM * 2);
  unsigned short* W2tl  = (unsigned short*)alloc((size_t)DIM * DIM * 2);
  unsigned short* Mth   = (unsigned short*)alloc((size_t)DIM * DIM * 2);

  // 0: weight prep + sentinel zeroing + pcnt zero
  k_prep<<<DIM * DIM / 256, 256, 0, stream>>>(W1, W2, M, W1th, W1tl, W2th, W2tl, Mth,
                                              hs, hbuf2, dv, pcnt);
  // 1: single-pass edge build (regs across hist->reserve->scatter) || decoder TQ || gemm1
  k_mega1<<<EB + G_TQ + G_GEMM, 256, 0, stream>>>(src, dst, pcnt, pe, Rel, Mth, Qbf,
                                                  init_emb, W1th, W1tl, hs);
  // 2: per-partition bucket fill (u16, pad-to-8) -> esrc + cnt + dinv
  k_build<<<NP, 256, 0, stream>>>(pe, pcnt, esrc, cnt, dv);
  // 3: pre-gather per-slot dinv -> edv (sequentializes agg's dv reads)
  k_edv<<<(N_NODES + 31) / 32, 256, 0, stream>>>(esrc, cnt, dv, edv);
  // 4: fused agg1 + gemm2 (each edge visited once; both slab planes; MFMA from LDS)
  k_agg_gemm2<<<N_NODES / 16, 256, 0, stream>>>(hs, cnt, dv, esrc, edv, b1, W2th, W2tl, hbuf2);
  // 5: agg2 only at batch positions -> compact planes (head fp32, tail bf16)
  k_agg_batch<<<(2 * BATCH + 7) / 8, 256, 0, stream>>>(hbuf2, cnt, dv, esrc, edv, b2, head, tail, pf, pth);
  // 6: predict (coalesced reads from compact planes)
  k_predict_mfma<<<dim3(BATCH / 128, N_REL), 256, 0, stream>>>(pf, pth, Qbf, out);
}